// Round 10
// baseline (283.170 us; speedup 1.0000x reference)
//
#include <hip/hip_runtime.h>
#include <cmath>
#include <cstdint>

// ---------------------------------------------------------------------------
// MWT for B=32, N=8192, c=16, k=4, modes=64.
// R14 structure (9 dispatches):
//   transpose_w ((m,o,i) layout),
//   twiddle_all (NOW LDS-tiled: coalesced uint4 stores for BOTH Ftw and Itw;
//                old Itw path was 2B-stores at 256B stride = 32x write amp),
//   dec_fused (L0..L3 fused; staged copy-out, 512 thr),
//   dec_deep (L4..L12 fused pyramid; 256 blocks x 8 cols, 512 thr),
//   fwd_all (bf16 MFMA, global_load_lds dbuf + XOR-swizzled tiles),
//   middle_all (bf16 MFMA, hi/lo-split A),
//   inv_all (bf16 MFMA; full-K levels: single-stage 64KB swizzled tiles),
//   recon_deep (t0 + i=12..4 fused; 256 blocks x 8 cols, 512 thr),
//   recon_fused (i=3..0 fused in LDS, 512 thr).
// Precision: x-chain fp32; spectral branch bf16 (contributions ~1e-3 scale).
// Lesson bank: staged contiguous global writes beat direct scattered stores
// (R7); stg bank conflicts NOT on critical path (R5); deep kernels were
// half-chip -> split to 256 (R13); Itw scatter was write-amplified (R14).
// ---------------------------------------------------------------------------

typedef __attribute__((ext_vector_type(8))) short bf16x8;
typedef __attribute__((ext_vector_type(4))) float f32x4;

struct Mat84 { float v[8][4]; };
struct Ptrs6 { const float* src[6]; uint16_t* dst[6]; };
struct TwLvls {
  int blkOff[14]; int Nl[13]; int l[13];
  unsigned long long fOff[13]; unsigned long long iOff[13];
};
struct FwdLvls {
  int blkOff[14]; int K[13]; int Kchunk[13];
  unsigned long long fOff[13]; unsigned long long bOff[13]; unsigned long long dOff[13];
};
struct MidLvls {
  int blkOff[14]; int l[13]; int nz[13];
  unsigned long long dOff[13]; unsigned long long sOff[13];
};
struct InvLvls {
  int blkOff[14]; int Nl[13]; int K2l[13];
  unsigned long long iOff[13]; unsigned long long sOff[13]; unsigned long long uOff[13];
};
struct DeepD { unsigned long long dsbOff[13]; };
struct DeepR { unsigned long long uOff[13]; };

__device__ __host__ inline uint16_t f2bf(float f) {
  union { float f; uint32_t u; } cv; cv.f = f;
  uint32_t u = cv.u;
  return (uint16_t)((u + 0x7fffu + ((u >> 16) & 1u)) >> 16);
}
__device__ inline float bf2f(uint16_t h) { return __uint_as_float((uint32_t)h << 16); }
__device__ inline uint32_t pack2(float a, float b) {
  return (uint32_t)f2bf(a) | ((uint32_t)f2bf(b) << 16);
}
__device__ inline bf16x8 negbf(bf16x8 x) {
  bf16x8 r;
#pragma unroll
  for (int j = 0; j < 8; j++) r[j] = (short)(x[j] ^ (short)0x8000);
  return r;
}
// Async global->LDS DMA, 16B per lane: LDS dest = uniform base + lane*16 (HW rule).
__device__ inline void gld_lds16(const uint16_t* g, uint16_t* l) {
  __builtin_amdgcn_global_load_lds(
      (const __attribute__((address_space(1))) void*)g,
      (__attribute__((address_space(3))) void*)l, 16, 0, 0);
}

// ---------------- host: Alpert/Legendre filter construction (k=4) ----------
static double proj_half_h(const double* a, const double* b, bool upper) {
  double prod[7] = {0, 0, 0, 0, 0, 0, 0};
  for (int i = 0; i < 4; i++)
    for (int j = 0; j < 4; j++)
      prod[i + j] += a[i] * b[j];
  for (int n = 0; n < 7; n++)
    if (fabs(prod[n]) < 1e-8) prod[n] = 0.0;
  double s = 0.0;
  for (int n = 0; n < 7; n++) {
    double w = upper ? (1.0 - pow(0.5, n + 1)) / (n + 1) : pow(0.5, n + 1) / (n + 1);
    s += prod[n] * w;
  }
  return s;
}
static double polyval4(const double* c, double x) {
  return c[0] + x * (c[1] + x * (c[2] + x * c[3]));
}

static void compute_filters(Mat84& ecs, Mat84& ecd, Mat84& rce, Mat84& rco) {
  const double leg[4][4] = {{1, 0, 0, 0}, {0, 1, 0, 0}, {-0.5, 0, 1.5, 0}, {0, -1.5, 0, 2.5}};
  double phi_c[4][4] = {}, phi2x_c[4][4] = {};
  const double s2 = sqrt(2.0);
  for (int ki = 0; ki < 4; ki++) {
    double a[4] = {0, 0, 0, 0};
    for (int j = 3; j >= 0; j--) {
      double na[4];
      for (int t = 0; t < 4; t++) { double v = -a[t]; if (t > 0) v += 2.0 * a[t - 1]; na[t] = v; }
      na[0] += leg[ki][j];
      for (int t = 0; t < 4; t++) a[t] = na[t];
    }
    for (int t = 0; t < 4; t++) phi_c[ki][t] = sqrt(2.0 * ki + 1.0) * a[t];
    double bb[4] = {0, 0, 0, 0};
    for (int j = 3; j >= 0; j--) {
      double nb[4];
      for (int t = 0; t < 4; t++) { double v = -bb[t]; if (t > 0) v += 4.0 * bb[t - 1]; nb[t] = v; }
      nb[0] += leg[ki][j];
      for (int t = 0; t < 4; t++) bb[t] = nb[t];
    }
    for (int t = 0; t < 4; t++) phi2x_c[ki][t] = s2 * sqrt(2.0 * ki + 1.0) * bb[t];
  }
  double psi1[4][4] = {}, psi2[4][4] = {};
  for (int ki = 0; ki < 4; ki++) {
    for (int t = 0; t < 4; t++) { psi1[ki][t] = phi2x_c[ki][t]; psi2[ki][t] = 0.0; }
    for (int i = 0; i < 4; i++) {
      double p = proj_half_h(phi2x_c[ki], phi_c[i], false);
      for (int t = 0; t < 4; t++) { psi1[ki][t] -= p * phi_c[i][t]; psi2[ki][t] -= p * phi_c[i][t]; }
    }
    for (int j = 0; j < ki; j++) {
      double p = proj_half_h(phi2x_c[ki], psi1[j], false);
      for (int t = 0; t < 4; t++) { psi1[ki][t] -= p * psi1[j][t]; psi2[ki][t] -= p * psi2[j][t]; }
    }
    double n1 = proj_half_h(psi1[ki], psi1[ki], false);
    double n2 = proj_half_h(psi2[ki], psi2[ki], true);
    double nr = sqrt(n1 + n2);
    for (int t = 0; t < 4; t++) { psi1[ki][t] /= nr; psi2[ki][t] /= nr; }
    for (int t = 0; t < 4; t++) {
      if (fabs(psi1[ki][t]) < 1e-8) psi1[ki][t] = 0.0;
      if (fabs(psi2[ki][t]) < 1e-8) psi2[ki][t] = 0.0;
    }
  }
  const double tq[4] = {-0.8611363115940526, -0.3399810435848563,
                        0.3399810435848563, 0.8611363115940526};
  const double wq[4] = {0.34785484513745385, 0.6521451548625461,
                        0.6521451548625461, 0.34785484513745385};
  double H0[4][4], H1[4][4], G0[4][4], G1[4][4];
  for (int ki = 0; ki < 4; ki++)
    for (int kp = 0; kp < 4; kp++) {
      double h0 = 0, h1 = 0, g0 = 0, g1 = 0;
      for (int m = 0; m < 4; m++) {
        double xm = (tq[m] + 1.0) * 0.5, wm = wq[m] * 0.5;
        double pk = polyval4(phi_c[kp], xm);
        h0 += wm * polyval4(phi_c[ki], xm * 0.5) * pk;
        h1 += wm * polyval4(phi_c[ki], (xm + 1.0) * 0.5) * pk;
        g0 += wm * polyval4(psi1[ki], xm * 0.5) * pk;
        g1 += wm * polyval4(psi2[ki], (xm + 1.0) * 0.5) * pk;
      }
      H0[ki][kp] = h0 / s2; H1[ki][kp] = h1 / s2; G0[ki][kp] = g0 / s2; G1[ki][kp] = g1 / s2;
    }
  for (int i = 0; i < 4; i++)
    for (int j = 0; j < 4; j++) {
      if (fabs(H0[i][j]) < 1e-8) H0[i][j] = 0.0;
      if (fabs(H1[i][j]) < 1e-8) H1[i][j] = 0.0;
      if (fabs(G0[i][j]) < 1e-8) G0[i][j] = 0.0;
      if (fabs(G1[i][j]) < 1e-8) G1[i][j] = 0.0;
    }
  for (int j = 0; j < 4; j++)
    for (int kk = 0; kk < 4; kk++) {
      ecs.v[j][kk]     = (float)H0[kk][j];
      ecs.v[j + 4][kk] = (float)H1[kk][j];
      ecd.v[j][kk]     = (float)G0[kk][j];
      ecd.v[j + 4][kk] = (float)G1[kk][j];
      rce.v[j][kk]     = (float)H0[j][kk];
      rce.v[j + 4][kk] = (float)G0[j][kk];
      rco.v[j][kk]     = (float)H1[j][kk];
      rco.v[j + 4][kk] = (float)G1[j][kk];
    }
}

// ---------------- device kernels -------------------------------------------

// Transpose weights (i,o,m) fp32 -> (m,o,i) bf16.
__global__ void transpose_w(Ptrs6 p) {
  __shared__ float tile[64][65];
  int o = blockIdx.x, a = blockIdx.y;
  const float* w = p.src[a];
  uint16_t* wt = p.dst[a];
  int mm = threadIdx.x & 63, irow = threadIdx.x >> 6;
  for (int i = irow; i < 64; i += 4) tile[i][mm] = w[(((size_t)i * 64 + o) << 6) + mm];
  __syncthreads();
  int ii = threadIdx.x & 63, mrow = threadIdx.x >> 6;
  for (int mq = mrow; mq < 64; mq += 4)
    wt[(((size_t)mq * 64 + o) << 6) + ii] = f2bf(tile[ii][mq]);
}

// All-level twiddles, LDS-tiled. Block = (level, 16-wide n-tile).
// Computes the 128 x 16 tile into LDS (ft linear; it stride-136), then
// copies out both matrices with uint4 stores: Ftw 32B row-chunks,
// Itw 256B contiguous rows. Values bitwise-identical to the old kernel.
__global__ __launch_bounds__(256) void twiddle_all(uint16_t* __restrict__ FtwB,
                                                   uint16_t* __restrict__ ItwB,
                                                   TwLvls tw) {
  __shared__ uint16_t ft[128 * 16];
  __shared__ uint16_t it[16 * 136];
  int bx = blockIdx.x;
  int L = 0;
  while (L < 12 && bx >= tw.blkOff[L + 1]) L++;
  int Nl = tw.Nl[L], l = tw.l[L];
  int n0 = (bx - tw.blkOff[L]) * 16;
  uint16_t* Ftw = FtwB + tw.fOff[L];
  uint16_t* Itw = ItwB + tw.iOff[L];
  int tid = threadIdx.x;
  for (int e = tid; e < 2048; e += 256) {
    int mm = e >> 4, nl = e & 15;
    int n = n0 + nl;
    float fv = 0.f, iv = 0.f;
    if (n < Nl && mm < 2 * l) {
      int m = (mm < l) ? mm : mm - l;
      int t = (m * n) & (Nl - 1);
      float ang = 6.2831853071795864769f * ((float)t / (float)Nl);
      float s, c;
      sincosf(ang, &s, &c);
      float cm = (m == 0 || 2 * m == Nl) ? 1.0f : 2.0f;
      float sc = cm / (float)Nl;
      if (mm < l) { fv = c;  iv = sc * c; }
      else        { fv = -s; iv = -sc * s; }
    }
    ft[mm * 16 + nl] = f2bf(fv);
    it[nl * 136 + mm] = f2bf(iv);
  }
  __syncthreads();
  if (n0 + 16 <= Nl) {
    // full tile: vector copy-out (256 threads cover both tiles exactly)
    {
      int mm = tid >> 1, half = tid & 1;
      *(uint4*)&Ftw[(size_t)mm * Nl + n0 + half * 8] = *(const uint4*)&ft[mm * 16 + half * 8];
    }
    {
      int nl = tid >> 4, q = tid & 15;
      *(uint4*)&Itw[(size_t)(n0 + nl) * 128 + q * 8] = *(const uint4*)&it[nl * 136 + q * 8];
    }
  } else {
    // partial tile (Nl < 16 levels): scalar guarded copy-out
    for (int e = tid; e < 2048; e += 256) {
      int mm = e >> 4, nl = e & 15;
      int n = n0 + nl;
      if (n < Nl) {
        Ftw[(size_t)mm * Nl + n] = ft[mm * 16 + nl];
        Itw[(size_t)n * 128 + mm] = it[nl * 136 + mm];
      }
    }
  }
}

// Fused decompose L0..L3: block = (b, c-chunk of 16 ch, n-tile of 256 L0-outputs).
// 512 threads (8 waves); staged copy-out (contiguous uint32 streams).
__global__ __launch_bounds__(512) void dec_fused(const float* __restrict__ xin,
                                                 uint16_t* __restrict__ DSbf,
                                                 float* __restrict__ sOut,
                                                 DeepD dd, Mat84 ecd, Mat84 ecs) {
  __shared__ float bufA[256 * 17];
  __shared__ float bufB[128 * 17];
  __shared__ uint16_t stg[32 * 256];
  int tid = threadIdx.x;
  int bx = blockIdx.x;
  int t = bx & 15, cc = (bx >> 4) & 3, b = bx >> 6;

  // ---- Level 0: global x -> bufA (s) + stg (d,s) ----
  {
    int nbase = t * 256;
    for (int e = tid; e < 1024; e += 512) {
      int n = e >> 2, lci = e & 3;
      const float* r0 = xin + ((size_t)b * 8192 + 2 * (nbase + n)) * 64 + cc * 16 + lci * 4;
      float4 xe = *(const float4*)r0;
      float4 xo = *(const float4*)(r0 + 64);
      float xa[8] = {xe.x, xe.y, xe.z, xe.w, xo.x, xo.y, xo.z, xo.w};
      float d[4] = {0, 0, 0, 0}, s[4] = {0, 0, 0, 0};
#pragma unroll
      for (int j = 0; j < 8; j++) {
        float v = xa[j];
#pragma unroll
        for (int kk = 0; kk < 4; kk++) {
          d[kk] = fmaf(v, ecd.v[j][kk], d[kk]);
          s[kk] = fmaf(v, ecs.v[j][kk], s[kk]);
        }
      }
#pragma unroll
      for (int kk = 0; kk < 4; kk++) {
        bufA[n * 17 + lci * 4 + kk] = s[kk];
        stg[(lci * 4 + kk) * 256 + n] = f2bf(d[kk]);
        stg[(16 + lci * 4 + kk) * 256 + n] = f2bf(s[kk]);
      }
    }
    __syncthreads();
    uint32_t* outu = (uint32_t*)(DSbf + dd.dsbOff[0]);
    const uint32_t* stgu = (const uint32_t*)stg;
    for (int e = tid; e < 32 * 128; e += 512) {
      int r = e >> 7, u = e & 127;
      int grow = (r < 16) ? (cc * 16 + r) : (64 + cc * 16 + (r - 16));
      outu[((((size_t)b * 128 + grow) * 4096 + nbase) >> 1) + u] = stgu[r * 128 + u];
    }
    __syncthreads();
  }
  // ---- Levels 1..3 (LDS pyramid) ----
  float* cur = bufA;
  float* nxt = bufB;
  int M = 128;
  for (int Lev = 1; Lev <= 3; Lev++) {
    int nbase = t * M;
    int Nl = 4096 >> Lev;
    for (int e = tid; e < M * 4; e += 512) {
      int n = e >> 2, lci = e & 3;
      float xa[8];
#pragma unroll
      for (int j = 0; j < 4; j++) {
        xa[j]     = cur[(2 * n) * 17 + lci * 4 + j];
        xa[4 + j] = cur[(2 * n + 1) * 17 + lci * 4 + j];
      }
      float d[4] = {0, 0, 0, 0}, s[4] = {0, 0, 0, 0};
#pragma unroll
      for (int j = 0; j < 8; j++) {
        float v = xa[j];
#pragma unroll
        for (int kk = 0; kk < 4; kk++) {
          d[kk] = fmaf(v, ecd.v[j][kk], d[kk]);
          s[kk] = fmaf(v, ecs.v[j][kk], s[kk]);
        }
      }
#pragma unroll
      for (int kk = 0; kk < 4; kk++) {
        if (Lev < 3) nxt[n * 17 + lci * 4 + kk] = s[kk];
        stg[(lci * 4 + kk) * 256 + n] = f2bf(d[kk]);
        stg[(16 + lci * 4 + kk) * 256 + n] = f2bf(s[kk]);
      }
      if (Lev == 3)
        *(float4*)&sOut[((size_t)b * 512 + nbase + n) * 64 + cc * 16 + lci * 4] =
            make_float4(s[0], s[1], s[2], s[3]);
    }
    __syncthreads();
    int cols = M >> 1, lg = 31 - __builtin_clz(cols);
    uint32_t* outu = (uint32_t*)(DSbf + dd.dsbOff[Lev]);
    const uint32_t* stgu = (const uint32_t*)stg;
    for (int e = tid; e < 32 * cols; e += 512) {
      int r = e >> lg, u = e & (cols - 1);
      int grow = (r < 16) ? (cc * 16 + r) : (64 + cc * 16 + (r - 16));
      outu[((((size_t)b * 128 + grow) * Nl + nbase) >> 1) + u] = stgu[r * 128 + u];
    }
    __syncthreads();
    float* tmp = cur; cur = nxt; nxt = tmp;
    M >>= 1;
  }
}

// Deep decompose: levels 4..12 fused. Block = (b, c-chunk of 2 c's = 8 cols),
// 256 blocks (1/CU). 512 threads. stg [16][258] (~2-way conflicts, free).
__global__ __launch_bounds__(512) void dec_deep(const float* __restrict__ sIn,
                                                uint16_t* __restrict__ DSbf,
                                                float* __restrict__ sFin,
                                                DeepD dd, Mat84 ecd, Mat84 ecs) {
  __shared__ float bufA[512 * 9];
  __shared__ float bufB[256 * 9];
  __shared__ uint16_t stg[16 * 258];
  int tid = threadIdx.x;
  int b = blockIdx.x >> 3, cc = blockIdx.x & 7;
  for (int e = tid; e < 512 * 2; e += 512) {
    int n = e >> 1, f4 = e & 1;
    float4 v = *(const float4*)&sIn[((size_t)b * 512 + n) * 64 + cc * 8 + f4 * 4];
    bufA[n * 9 + f4 * 4 + 0] = v.x;
    bufA[n * 9 + f4 * 4 + 1] = v.y;
    bufA[n * 9 + f4 * 4 + 2] = v.z;
    bufA[n * 9 + f4 * 4 + 3] = v.w;
  }
  __syncthreads();
  float* cur = bufA;
  float* nxt = bufB;
  int len = 512;
  for (int L = 4; L <= 12; L++) {
    int M = len >> 1;
    for (int e = tid; e < M * 2; e += 512) {
      int n = e >> 1, cl = e & 1;
      float xa[8];
#pragma unroll
      for (int j = 0; j < 4; j++) {
        xa[j]     = cur[(2 * n) * 9 + cl * 4 + j];
        xa[4 + j] = cur[(2 * n + 1) * 9 + cl * 4 + j];
      }
      float d[4] = {0, 0, 0, 0}, s[4] = {0, 0, 0, 0};
#pragma unroll
      for (int j = 0; j < 8; j++) {
        float v = xa[j];
#pragma unroll
        for (int kk = 0; kk < 4; kk++) {
          d[kk] = fmaf(v, ecd.v[j][kk], d[kk]);
          s[kk] = fmaf(v, ecs.v[j][kk], s[kk]);
        }
      }
#pragma unroll
      for (int kk = 0; kk < 4; kk++) {
        nxt[n * 9 + cl * 4 + kk] = s[kk];
        stg[(cl * 4 + kk) * 258 + n] = f2bf(d[kk]);
        stg[(8 + cl * 4 + kk) * 258 + n] = f2bf(s[kk]);
      }
    }
    __syncthreads();
    uint16_t* out = DSbf + dd.dsbOff[L];
    if (M >= 2) {
      int M2 = M >> 1;
      int lg = 31 - __builtin_clz(M2);
      uint32_t* outu = (uint32_t*)out;
      const uint32_t* stgu = (const uint32_t*)stg;
      for (int e = tid; e < 16 * M2; e += 512) {
        int r = e >> lg, u = e & (M2 - 1);
        int grow = (r < 8) ? (cc * 8 + r) : (64 + cc * 8 + (r - 8));
        outu[(((size_t)b * 128 + grow) * M >> 1) + u] = stgu[r * 129 + u];
      }
    } else {
      for (int e = tid; e < 16; e += 512) {
        int grow = (e < 8) ? (cc * 8 + e) : (64 + cc * 8 + (e - 8));
        out[(size_t)b * 128 + grow] = stg[e * 258];
      }
    }
    __syncthreads();
    float* t = cur; cur = nxt; nxt = t;
    len = M;
  }
  for (int e = tid; e < 8; e += 512) sFin[(size_t)b * 64 + cc * 8 + e] = cur[e];
}

// Fwd DFT GEMM, all levels: Dfs slab (z,b) = Ftw(128xK) @ DSbf_b^T chunk.
__global__ __launch_bounds__(256) void fwd_all(const uint16_t* __restrict__ FtwB,
                                               const uint16_t* __restrict__ DSbfB,
                                               float* __restrict__ DfsB, FwdLvls fl) {
  __shared__ uint16_t As[2][4096];
  __shared__ uint16_t Bs[2][4096];
  int bx = blockIdx.x, L = 0;
  while (L < 12 && bx >= fl.blkOff[L + 1]) L++;
  int local = bx - fl.blkOff[L];
  int b = local & 31, z = local >> 5;
  int K = fl.K[L];
  int k0 = z * fl.Kchunk[L];
  int k1 = k0 + fl.Kchunk[L]; if (k1 > K) k1 = K;
  const uint16_t* A = FtwB + fl.fOff[L];
  const uint16_t* Bb = DSbfB + fl.bOff[L] + (size_t)b * 128 * K;
  int tid = threadIdx.x;
  int w = tid >> 6, lane = tid & 63;
  int wr = w >> 1, wc = w & 1;
  int lr = lane & 15, q = lane >> 4;
  f32x4 acc[4][4];
#pragma unroll
  for (int i = 0; i < 4; i++)
#pragma unroll
    for (int j = 0; j < 4; j++) acc[i][j] = (f32x4){0.f, 0.f, 0.f, 0.f};

  if (K >= 32) {
    int rsub = lane >> 2, g = lane & 3;
    int nsteps = (k1 - k0) >> 5;
    auto stage = [&](int buf, int kc) {
#pragma unroll
      for (int j = 0; j < 2; ++j) {
        int c = w * 2 + j;
        int row = c * 16 + rsub;
        int gs = (g ^ ((row >> 1) & 3)) << 3;
        gld_lds16(A + (size_t)row * K + kc + gs, &As[buf][c * 512]);
        gld_lds16(Bb + (size_t)row * K + kc + gs, &Bs[buf][c * 512]);
      }
    };
    stage(0, k0);
    __syncthreads();
    int cur = 0;
    int sw = (lr >> 1) & 3;
    for (int s = 0; s < nsteps; ++s) {
      if (s + 1 < nsteps) stage(cur ^ 1, k0 + ((s + 1) << 5));
      bf16x8 af[4], bfv[4];
#pragma unroll
      for (int t = 0; t < 4; t++) {
        af[t]  = *(const bf16x8*)&As[cur][(wr * 64 + t * 16 + lr) * 32 + ((q ^ sw) << 3)];
        bfv[t] = *(const bf16x8*)&Bs[cur][(wc * 64 + t * 16 + lr) * 32 + ((q ^ sw) << 3)];
      }
#pragma unroll
      for (int mt = 0; mt < 4; mt++)
#pragma unroll
        for (int nt = 0; nt < 4; nt++)
          acc[mt][nt] = __builtin_amdgcn_mfma_f32_16x16x32_bf16(af[mt], bfv[nt], acc[mt][nt], 0, 0, 0);
      __syncthreads();
      cur ^= 1;
    }
  } else {
    for (int s = tid; s < 512; s += 256) {
      int row = s >> 2, k8 = (s & 3) * 8;
      uint16_t ta[8], tb[8];
#pragma unroll
      for (int j = 0; j < 8; j++) {
        ta[j] = (k8 + j < k1) ? A[(size_t)row * K + k8 + j] : (uint16_t)0;
        tb[j] = (k8 + j < k1) ? Bb[(size_t)row * K + k8 + j] : (uint16_t)0;
      }
      *(uint4*)&As[0][row * 32 + k8] = *(const uint4*)ta;
      *(uint4*)&Bs[0][row * 32 + k8] = *(const uint4*)tb;
    }
    __syncthreads();
    bf16x8 af[4], bfv[4];
#pragma unroll
    for (int t = 0; t < 4; t++) {
      af[t]  = *(const bf16x8*)&As[0][(wr * 64 + t * 16 + lr) * 32 + q * 8];
      bfv[t] = *(const bf16x8*)&Bs[0][(wc * 64 + t * 16 + lr) * 32 + q * 8];
    }
#pragma unroll
    for (int mt = 0; mt < 4; mt++)
#pragma unroll
      for (int nt = 0; nt < 4; nt++)
        acc[mt][nt] = __builtin_amdgcn_mfma_f32_16x16x32_bf16(af[mt], bfv[nt], acc[mt][nt], 0, 0, 0);
  }

  float* Cb = DfsB + fl.dOff[L] + ((size_t)z * 32 + b) * 16384;
#pragma unroll
  for (int mt = 0; mt < 4; mt++) {
    int row0 = wr * 64 + mt * 16 + q * 4;
#pragma unroll
    for (int nt = 0; nt < 4; nt++) {
      int col = wc * 64 + nt * 16 + lr;
#pragma unroll
      for (int r = 0; r < 4; r++)
        Cb[(size_t)(row0 + r) * 128 + col] = acc[mt][nt][r];
    }
  }
}

// Spectral mix, all levels — MFMA version.
__global__ __launch_bounds__(256) void middle_all(
    const float* __restrict__ DfsB,
    const uint16_t* __restrict__ wAr, const uint16_t* __restrict__ wAi,
    const uint16_t* __restrict__ wBr, const uint16_t* __restrict__ wBi,
    const uint16_t* __restrict__ wCr, const uint16_t* __restrict__ wCi,
    uint16_t* __restrict__ SpecTB, MidLvls ml) {
  __shared__ uint16_t Bs[6 * 64 * 64];
  __shared__ uint16_t As[8 * 32 * 64];
  int bx = blockIdx.x, L = 0;
  while (L < 12 && bx >= ml.blkOff[L + 1]) L++;
  int m = bx - ml.blkOff[L];
  int l = ml.l[L], nz = ml.nz[L];
  const float* Dfs = DfsB + ml.dOff[L];
  uint16_t* SpecT = SpecTB + ml.sOff[L];
  int tid = threadIdx.x;

#pragma unroll
  for (int a = 0; a < 6; a++) {
    const uint16_t* wpa = (a == 0) ? wAr : (a == 1) ? wAi : (a == 2) ? wBr
                        : (a == 3) ? wBi : (a == 4) ? wCr : wCi;
#pragma unroll
    for (int t0 = 0; t0 < 512; t0 += 256) {
      int t = t0 + tid;
      int o = t >> 3, g = t & 7;
      uint4 v = *(const uint4*)&wpa[(((size_t)m * 64 + o) << 6) + (g << 3)];
      *(uint4*)((char*)Bs + a * 8192 + o * 128 + (((g ^ (o & 7)) << 4))) = v;
    }
  }
  for (int e = tid; e < 2048; e += 256) {
    int c4 = (e & 31) * 4, r = (e >> 5) & 1, bb = e >> 6;
    size_t row = r ? (size_t)(l + m) : (size_t)m;
    float4 s = make_float4(0.f, 0.f, 0.f, 0.f);
    for (int z = 0; z < nz; z++) {
      float4 v = *(const float4*)&Dfs[((((size_t)z * 32 + bb) * 128 + row) << 7) + c4];
      s.x += v.x; s.y += v.y; s.z += v.z; s.w += v.w;
    }
    int vec = r + ((c4 >= 64) ? 2 : 0);
    int i0 = c4 & 63;
    float f[4] = {s.x, s.y, s.z, s.w};
    uint16_t hi[4], lo[4];
#pragma unroll
    for (int j = 0; j < 4; j++) {
      hi[j] = f2bf(f[j]);
      lo[j] = f2bf(f[j] - bf2f(hi[j]));
    }
    int g = i0 >> 3, w8 = (i0 & 7) * 2;
    char* ph = (char*)As + ((vec * 2 + 0) * 32 + bb) * 128 + ((g ^ (bb & 7)) << 4) + w8;
    char* pl = (char*)As + ((vec * 2 + 1) * 32 + bb) * 128 + ((g ^ (bb & 7)) << 4) + w8;
    *(uint2*)ph = make_uint2((uint32_t)hi[0] | ((uint32_t)hi[1] << 16),
                             (uint32_t)hi[2] | ((uint32_t)hi[3] << 16));
    *(uint2*)pl = make_uint2((uint32_t)lo[0] | ((uint32_t)lo[1] << 16),
                             (uint32_t)lo[2] | ((uint32_t)lo[3] << 16));
  }
  __syncthreads();

  int w = tid >> 6, lane = tid & 63;
  int lr = lane & 15, q = lane >> 4;
  f32x4 acc[2][4];
#pragma unroll
  for (int i = 0; i < 2; i++)
#pragma unroll
    for (int j = 0; j < 4; j++) acc[i][j] = (f32x4){0.f, 0.f, 0.f, 0.f};

  auto combo = [&](int v, int a, int ng) {
    bf16x8 bf[4][2];
#pragma unroll
    for (int nt = 0; nt < 4; nt++) {
      int o = nt * 16 + lr;
#pragma unroll
      for (int ks = 0; ks < 2; ks++) {
        int g = ks * 4 + q;
        bf[nt][ks] = *(const bf16x8*)((const char*)Bs + a * 8192 + o * 128 +
                                      ((g ^ (o & 7)) << 4));
      }
    }
#pragma unroll
    for (int p = 0; p < 2; p++) {
#pragma unroll
      for (int mt = 0; mt < 2; mt++) {
        int bb = mt * 16 + lr;
        const char* ab = (const char*)As + ((v * 2 + p) * 32 + bb) * 128;
        bf16x8 a0 = *(const bf16x8*)(ab + (((0 + q) ^ (bb & 7)) << 4));
        bf16x8 a1 = *(const bf16x8*)(ab + (((4 + q) ^ (bb & 7)) << 4));
        if (ng) { a0 = negbf(a0); a1 = negbf(a1); }
#pragma unroll
        for (int nt = 0; nt < 4; nt++) {
          acc[mt][nt] = __builtin_amdgcn_mfma_f32_16x16x32_bf16(a0, bf[nt][0], acc[mt][nt], 0, 0, 0);
          acc[mt][nt] = __builtin_amdgcn_mfma_f32_16x16x32_bf16(a1, bf[nt][1], acc[mt][nt], 0, 0, 0);
        }
      }
    }
  };
  if (w == 0) {
    combo(0, 0, 0); combo(1, 1, 1); combo(2, 2, 0); combo(3, 3, 1);
  } else if (w == 1) {
    combo(1, 0, 0); combo(0, 1, 0); combo(3, 2, 0); combo(2, 3, 0);
  } else if (w == 2) {
    combo(0, 4, 0); combo(1, 5, 1);
  } else {
    combo(1, 4, 0); combo(0, 5, 0);
  }

  int krow = (w & 1) ? (l + m) : m;
  int colbase = (w >= 2) ? 64 : 0;
#pragma unroll
  for (int mt = 0; mt < 2; mt++) {
#pragma unroll
    for (int nt = 0; nt < 4; nt++) {
#pragma unroll
      for (int r = 0; r < 4; r++) {
        int bb = mt * 16 + q * 4 + r;
        int oo = nt * 16 + lr;
        SpecT[((size_t)bb * 128 + colbase + oo) * 128 + krow] = f2bf(acc[mt][nt][r]);
      }
    }
  }
}

// Inv DFT GEMM, all levels: Y_b (Nl x 128) = Itw(Nl x 128) @ Spec_b (128x128).
__global__ __launch_bounds__(256) void inv_all(const uint16_t* __restrict__ ItwB,
                                               const uint16_t* __restrict__ SpecTB,
                                               uint16_t* __restrict__ UdB,
                                               uint16_t* __restrict__ UsB, InvLvls il) {
  __shared__ uint16_t lds[32768];
  int bx = blockIdx.x, L = 0;
  while (L < 12 && bx >= il.blkOff[L + 1]) L++;
  int local = bx - il.blkOff[L];
  int b = local & 31, n0 = (local >> 5) * 128;
  int Nl = il.Nl[L], K2l = il.K2l[L];
  const uint16_t* A = ItwB + il.iOff[L];
  const uint16_t* Bb = SpecTB + il.sOff[L] + (size_t)b * 128 * 128;
  uint16_t* Ud = UdB + il.uOff[L];
  uint16_t* Us = UsB + il.uOff[L];
  int tid = threadIdx.x;
  int w = tid >> 6, lane = tid & 63;
  int wr = w >> 1, wc = w & 1;
  int lr = lane & 15, q = lane >> 4;
  f32x4 acc[4][4];
#pragma unroll
  for (int i = 0; i < 4; i++)
#pragma unroll
    for (int j = 0; j < 4; j++) acc[i][j] = (f32x4){0.f, 0.f, 0.f, 0.f};

  if (K2l == 128) {
    uint16_t* As0 = lds;
    uint16_t* Bs0 = lds + 16384;
    int rsub = lane >> 4, p = lane & 15;
#pragma unroll
    for (int i = 0; i < 8; i++) {
      int rowb = w * 32 + i * 4;
      int row = rowb + rsub;
      int gs = (p ^ (row & 7)) << 3;
      gld_lds16(A + (size_t)(n0 + row) * 128 + gs, As0 + rowb * 128);
      gld_lds16(Bb + (size_t)row * 128 + gs, Bs0 + rowb * 128);
    }
    __syncthreads();
    int sw = lr & 7;
#pragma unroll
    for (int kc = 0; kc < 4; kc++) {
      bf16x8 af[4], bfv[4];
#pragma unroll
      for (int t = 0; t < 4; t++) {
        int g = kc * 4 + q;
        af[t]  = *(const bf16x8*)&As0[(wr * 64 + t * 16 + lr) * 128 + ((g ^ sw) << 3)];
        bfv[t] = *(const bf16x8*)&Bs0[(wc * 64 + t * 16 + lr) * 128 + ((g ^ sw) << 3)];
      }
#pragma unroll
      for (int mt = 0; mt < 4; mt++)
#pragma unroll
        for (int nt = 0; nt < 4; nt++)
          acc[mt][nt] = __builtin_amdgcn_mfma_f32_16x16x32_bf16(af[mt], bfv[nt], acc[mt][nt], 0, 0, 0);
    }
    __syncthreads();
#pragma unroll
    for (int mt = 0; mt < 4; mt++)
#pragma unroll
      for (int nt = 0; nt < 4; nt++)
#pragma unroll
        for (int r = 0; r < 4; r++)
          lds[(wr * 64 + mt * 16 + q * 4 + r) * 132 + wc * 64 + nt * 16 + lr] =
              f2bf(acc[mt][nt][r]);
    __syncthreads();
    uint16_t* Udb = Ud + ((size_t)b * Nl + n0) * 64;
    uint16_t* Usb = Us + ((size_t)b * Nl + n0) * 64;
#pragma unroll
    for (int i = 0; i < 4; i++) {
      int f = i * 256 + tid;
      int row = f >> 3, c8 = (f & 7) * 8;
      *(uint4*)(Udb + (size_t)f * 8) = *(const uint4*)&lds[row * 132 + c8];
      *(uint4*)(Usb + (size_t)f * 8) = *(const uint4*)&lds[row * 132 + 64 + c8];
    }
    return;
  }

  uint16_t* As0 = lds;
  uint16_t* Bs0 = lds + 4096;
  for (int kc = 0; kc < 128; kc += 32) {
    for (int s = tid; s < 512; s += 256) {
      int row = s >> 2, k8 = (s & 3) * 8;
      int kg = kc + k8;
      *(uint4*)&As0[row * 32 + k8] = *(const uint4*)&A[((size_t)(n0 + row)) * 128 + kg];
      uint16_t tb[8];
      if (kg + 8 <= K2l) {
        *(uint4*)tb = *(const uint4*)&Bb[(size_t)row * 128 + kg];
      } else {
#pragma unroll
        for (int j = 0; j < 8; j++)
          tb[j] = (kg + j < K2l) ? Bb[(size_t)row * 128 + kg + j] : (uint16_t)0;
      }
      *(uint4*)&Bs0[row * 32 + k8] = *(const uint4*)tb;
    }
    __syncthreads();
    bf16x8 af[4], bfv[4];
#pragma unroll
    for (int t = 0; t < 4; t++) {
      af[t]  = *(const bf16x8*)&As0[(wr * 64 + t * 16 + lr) * 32 + q * 8];
      bfv[t] = *(const bf16x8*)&Bs0[(wc * 64 + t * 16 + lr) * 32 + q * 8];
    }
#pragma unroll
    for (int mt = 0; mt < 4; mt++)
#pragma unroll
      for (int nt = 0; nt < 4; nt++)
        acc[mt][nt] = __builtin_amdgcn_mfma_f32_16x16x32_bf16(af[mt], bfv[nt], acc[mt][nt], 0, 0, 0);
    __syncthreads();
  }
#pragma unroll
  for (int mt = 0; mt < 4; mt++) {
    int row0 = wr * 64 + mt * 16 + q * 4;
#pragma unroll
    for (int nt = 0; nt < 4; nt++) {
      int col = wc * 64 + nt * 16 + lr;
#pragma unroll
      for (int r = 0; r < 4; r++) {
        int n = n0 + row0 + r;
        if (n < Nl) {
          uint16_t v = f2bf(acc[mt][nt][r]);
          if (col < 64) Ud[((size_t)b * Nl + n) * 64 + col] = v;
          else          Us[((size_t)b * Nl + n) * 64 + (col - 64)] = v;
        }
      }
    }
  }
}

// Deep recon: t0 on s^13, then levels i=12..4 fused. Block = (b, 8-col chunk),
// 256 blocks, 512 threads; writes x^4 (b, 512, 64) fp32.
__global__ __launch_bounds__(512) void recon_deep(const float* __restrict__ sFin,
                                                  const float* __restrict__ t0w,
                                                  const float* __restrict__ t0b,
                                                  const uint16_t* __restrict__ UdB,
                                                  const uint16_t* __restrict__ UsB,
                                                  float* __restrict__ xOut,
                                                  DeepR rl, Mat84 rce, Mat84 rco) {
  __shared__ float bufA[512 * 9];
  __shared__ float bufB[256 * 9];
  int tid = threadIdx.x;
  int b = blockIdx.x >> 3, cc = blockIdx.x & 7;
  if (tid < 8) {
    int cl = tid >> 2, kk = tid & 3;
    const float* sp = sFin + (size_t)b * 64 + cc * 8 + cl * 4;
    float v = t0b[kk];
#pragma unroll
    for (int k2 = 0; k2 < 4; k2++) v += t0w[kk * 4 + k2] * sp[k2];
    bufB[cl * 4 + kk] = v;
  }
  __syncthreads();
  float* cur = bufB;
  float* nxt = bufA;
  int M = 1;
  for (int i = 12; i >= 4; i--) {
    const uint16_t* Ud = UdB + rl.uOff[i];
    const uint16_t* Us = UsB + rl.uOff[i];
    for (int e = tid; e < M * 2; e += 512) {
      int n = e >> 1, cl = e & 1;
      size_t ua = ((size_t)b * M + n) * 64 + cc * 8 + cl * 4;
      ushort4 uu = *(const ushort4*)&Us[ua];
      ushort4 dd = *(const ushort4*)&Ud[ua];
      float t[8];
      t[0] = cur[n * 9 + cl * 4 + 0] + bf2f(uu.x);
      t[1] = cur[n * 9 + cl * 4 + 1] + bf2f(uu.y);
      t[2] = cur[n * 9 + cl * 4 + 2] + bf2f(uu.z);
      t[3] = cur[n * 9 + cl * 4 + 3] + bf2f(uu.w);
      t[4] = bf2f(dd.x); t[5] = bf2f(dd.y); t[6] = bf2f(dd.z); t[7] = bf2f(dd.w);
      float ev[4] = {0, 0, 0, 0}, ov[4] = {0, 0, 0, 0};
#pragma unroll
      for (int j = 0; j < 8; j++) {
        float v = t[j];
#pragma unroll
        for (int kk = 0; kk < 4; kk++) {
          ev[kk] = fmaf(v, rce.v[j][kk], ev[kk]);
          ov[kk] = fmaf(v, rco.v[j][kk], ov[kk]);
        }
      }
#pragma unroll
      for (int kk = 0; kk < 4; kk++) {
        nxt[(2 * n) * 9 + cl * 4 + kk] = ev[kk];
        nxt[(2 * n + 1) * 9 + cl * 4 + kk] = ov[kk];
      }
    }
    __syncthreads();
    float* t = cur; cur = nxt; nxt = t;
    M <<= 1;
  }
  for (int e = tid; e < 512 * 2; e += 512) {
    int n = e >> 1, f4 = e & 1;
    float4 v = make_float4(cur[n * 9 + f4 * 4 + 0], cur[n * 9 + f4 * 4 + 1],
                           cur[n * 9 + f4 * 4 + 2], cur[n * 9 + f4 * 4 + 3]);
    *(float4*)&xOut[((size_t)b * 512 + n) * 64 + cc * 8 + f4 * 4] = v;
  }
}

// Fused recon i=3..0: block = (b, c-chunk of 16 ch, tile of 512 final rows).
// 512 threads.
__global__ __launch_bounds__(512) void recon_fused(const float* __restrict__ xin,
                                                   const uint16_t* __restrict__ UdB,
                                                   const uint16_t* __restrict__ UsB,
                                                   float* __restrict__ out,
                                                   DeepR rl, Mat84 rce, Mat84 rco) {
  __shared__ float bufA[256 * 17];
  __shared__ float bufB[256 * 17];
  int tid = threadIdx.x;
  int bx = blockIdx.x;
  int t = bx & 15, cc = (bx >> 4) & 3, b = bx >> 6;

  // ---- i = 3: SD (32 rows) -> bufA (64 rows) ----
  {
    int nbase = t * 32;
    const uint16_t* Ud = UdB + rl.uOff[3];
    const uint16_t* Us = UsB + rl.uOff[3];
    for (int e = tid; e < 128; e += 512) {
      int n = e >> 2, lci = e & 3;
      size_t ua = ((size_t)b * 512 + nbase + n) * 64 + cc * 16 + lci * 4;
      float4 xv = *(const float4*)&xin[ua];
      ushort4 uu = *(const ushort4*)&Us[ua];
      ushort4 dd = *(const ushort4*)&Ud[ua];
      float tv[8] = {xv.x + bf2f(uu.x), xv.y + bf2f(uu.y), xv.z + bf2f(uu.z),
                     xv.w + bf2f(uu.w), bf2f(dd.x), bf2f(dd.y), bf2f(dd.z), bf2f(dd.w)};
      float ev[4] = {0, 0, 0, 0}, ov[4] = {0, 0, 0, 0};
#pragma unroll
      for (int j = 0; j < 8; j++) {
        float v = tv[j];
#pragma unroll
        for (int kk = 0; kk < 4; kk++) {
          ev[kk] = fmaf(v, rce.v[j][kk], ev[kk]);
          ov[kk] = fmaf(v, rco.v[j][kk], ov[kk]);
        }
      }
#pragma unroll
      for (int kk = 0; kk < 4; kk++) {
        bufA[(2 * n) * 17 + lci * 4 + kk] = ev[kk];
        bufA[(2 * n + 1) * 17 + lci * 4 + kk] = ov[kk];
      }
    }
    __syncthreads();
  }
  // ---- i = 2, 1, 0 ----
  float* cur = bufA;
  float* nxt = bufB;
  int m = 64;
  for (int i = 2; i >= 0; i--) {
    int Mlev = 8192 >> (i + 1);
    int nbase = t * m;
    const uint16_t* Ud = UdB + rl.uOff[i];
    const uint16_t* Us = UsB + rl.uOff[i];
    for (int e = tid; e < m * 4; e += 512) {
      int n = e >> 2, lci = e & 3;
      size_t ua = ((size_t)b * Mlev + nbase + n) * 64 + cc * 16 + lci * 4;
      ushort4 uu = *(const ushort4*)&Us[ua];
      ushort4 dd = *(const ushort4*)&Ud[ua];
      float tv[8];
      tv[0] = cur[n * 17 + lci * 4 + 0] + bf2f(uu.x);
      tv[1] = cur[n * 17 + lci * 4 + 1] + bf2f(uu.y);
      tv[2] = cur[n * 17 + lci * 4 + 2] + bf2f(uu.z);
      tv[3] = cur[n * 17 + lci * 4 + 3] + bf2f(uu.w);
      tv[4] = bf2f(dd.x); tv[5] = bf2f(dd.y); tv[6] = bf2f(dd.z); tv[7] = bf2f(dd.w);
      float ev[4] = {0, 0, 0, 0}, ov[4] = {0, 0, 0, 0};
#pragma unroll
      for (int j = 0; j < 8; j++) {
        float v = tv[j];
#pragma unroll
        for (int kk = 0; kk < 4; kk++) {
          ev[kk] = fmaf(v, rce.v[j][kk], ev[kk]);
          ov[kk] = fmaf(v, rco.v[j][kk], ov[kk]);
        }
      }
      if (i > 0) {
#pragma unroll
        for (int kk = 0; kk < 4; kk++) {
          nxt[(2 * n) * 17 + lci * 4 + kk] = ev[kk];
          nxt[(2 * n + 1) * 17 + lci * 4 + kk] = ov[kk];
        }
      } else {
        size_t ob = ((size_t)b * 8192 + 2 * (nbase + n)) * 64 + cc * 16 + lci * 4;
        *(float4*)&out[ob] = make_float4(ev[0], ev[1], ev[2], ev[3]);
        *(float4*)&out[ob + 64] = make_float4(ov[0], ov[1], ov[2], ov[3]);
      }
    }
    __syncthreads();
    float* tmp = cur; cur = nxt; nxt = tmp;
    m <<= 1;
  }
}

// ---------------- host orchestration ---------------------------------------
extern "C" void kernel_launch(void* const* d_in, const int* in_sizes, int n_in,
                              void* d_out, int out_size, void* d_ws, size_t ws_size,
                              hipStream_t stream) {
  const float* x_in = (const float*)d_in[0];
  const float* t0w = (const float*)d_in[7];
  const float* t0b = (const float*)d_in[8];

  Mat84 ECS, ECD, RCE, RCO;
  compute_filters(ECS, ECD, RCE, RCO);

  int NlA[13], lA[13], nzA[13], KchA[13];
  size_t fOff[13], iOff[13], uOffA[13], dsbOff[13], dOff[13], sOff[13];
  size_t fo = 0, io = 0, uo = 0, db = 0, df = 0;
  for (int L = 0; L < 13; L++) {
    int Nl = 8192 >> (L + 1);
    int l = Nl / 2 + 1; if (l > 64) l = 64;
    NlA[L] = Nl; lA[L] = l;
    nzA[L] = (L == 0) ? 4 : (L == 1) ? 2 : 1;
    KchA[L] = Nl / nzA[L];
    fOff[L] = fo; fo += (size_t)128 * Nl;
    iOff[L] = io; io += (size_t)Nl * 128;
    uOffA[L] = uo; uo += (size_t)32 * 64 * Nl;
    dsbOff[L] = db; db += (size_t)32 * 128 * Nl;
    dOff[L] = df; df += (size_t)nzA[L] * 32 * 128 * 128;
    sOff[L] = (size_t)L * 32 * 128 * 128;
  }
  io += 128 * 128;  // inv_all A-row overrun slack at partial tiles

  char* base = (char*)d_ws;
  size_t off = 0;
  auto alloc = [&](size_t bytes) -> char* {
    char* p = base + off;
    off += (bytes + 255) & ~(size_t)255;
    return p;
  };
  float*    SD    = (float*)alloc((size_t)32 * 512 * 64 * 4);
  float*    SFin  = (float*)alloc((size_t)32 * 64 * 4);
  uint16_t* Ud    = (uint16_t*)alloc(uo * 2);
  uint16_t* Us    = (uint16_t*)alloc(uo * 2);
  float*    Dfs   = (float*)alloc(df * 4);
  uint16_t* SpecT = (uint16_t*)alloc((size_t)13 * 32 * 128 * 128 * 2);
  uint16_t* DSbf  = (uint16_t*)alloc(db * 2);
  uint16_t* Ftw   = (uint16_t*)alloc(fo * 2);
  uint16_t* Itw   = (uint16_t*)alloc(io * 2);
  uint16_t* wT[6];
  for (int a = 0; a < 6; a++) wT[a] = (uint16_t*)alloc((size_t)64 * 64 * 64 * 2);

  // 1: weights -> (m, o, i) bf16
  Ptrs6 p6;
  for (int a = 0; a < 6; a++) { p6.src[a] = (const float*)d_in[1 + a]; p6.dst[a] = wT[a]; }
  transpose_w<<<dim3(64, 6), 256, 0, stream>>>(p6);

  // 2: twiddles (16-wide n-tiles per level)
  TwLvls tw;
  int bo = 0;
  for (int L = 0; L < 13; L++) {
    tw.blkOff[L] = bo;
    bo += (NlA[L] + 15) / 16;
    tw.Nl[L] = NlA[L]; tw.l[L] = lA[L];
    tw.fOff[L] = fOff[L]; tw.iOff[L] = iOff[L];
  }
  tw.blkOff[13] = bo;
  twiddle_all<<<bo, 256, 0, stream>>>(Ftw, Itw, tw);

  DeepD dd;
  for (int L = 0; L < 13; L++) dd.dsbOff[L] = dsbOff[L];

  // 3: fused decompose L0..L3 (512 threads)
  dec_fused<<<2048, 512, 0, stream>>>(x_in, DSbf, SD, dd, ECD, ECS);

  // 4: deep decompose L4..L12 (256 blocks x 512 threads)
  dec_deep<<<256, 512, 0, stream>>>(SD, DSbf, SFin, dd, ECD, ECS);

  // 5: fwd GEMM all levels
  FwdLvls fl;
  bo = 0;
  for (int L = 0; L < 13; L++) {
    fl.blkOff[L] = bo; bo += 32 * nzA[L];
    fl.K[L] = NlA[L]; fl.Kchunk[L] = KchA[L];
    fl.fOff[L] = fOff[L]; fl.bOff[L] = dsbOff[L]; fl.dOff[L] = dOff[L];
  }
  fl.blkOff[13] = bo;
  fwd_all<<<bo, 256, 0, stream>>>(Ftw, DSbf, Dfs, fl);

  // 6: spectral mix all levels
  MidLvls ml;
  bo = 0;
  for (int L = 0; L < 13; L++) {
    ml.blkOff[L] = bo; bo += lA[L];
    ml.l[L] = lA[L]; ml.nz[L] = nzA[L];
    ml.dOff[L] = dOff[L]; ml.sOff[L] = sOff[L];
  }
  ml.blkOff[13] = bo;
  middle_all<<<bo, 256, 0, stream>>>(Dfs, wT[0], wT[1], wT[2], wT[3], wT[4], wT[5], SpecT, ml);

  // 7: inv GEMM all levels
  InvLvls il;
  bo = 0;
  for (int L = 0; L < 13; L++) {
    il.blkOff[L] = bo; bo += ((NlA[L] + 127) / 128) * 32;
    il.Nl[L] = NlA[L]; il.K2l[L] = 2 * lA[L];
    il.iOff[L] = iOff[L]; il.sOff[L] = sOff[L]; il.uOff[L] = uOffA[L];
  }
  il.blkOff[13] = bo;
  inv_all<<<bo, 256, 0, stream>>>(Itw, SpecT, Ud, Us, il);

  DeepR rl;
  for (int L = 0; L < 13; L++) rl.uOff[L] = uOffA[L];

  // 8: deep recon (t0 + i=12..4) -> x^4 in SD (256 blocks x 512 threads)
  recon_deep<<<256, 512, 0, stream>>>(SFin, t0w, t0b, Ud, Us, SD, rl, RCE, RCO);

  // 9: fused recon i=3..0 -> output (512 threads)
  recon_fused<<<2048, 512, 0, stream>>>(SD, Ud, Us, (float*)d_out, rl, RCE, RCO);
}

// Round 11
// 273.934 us; speedup vs baseline: 1.0337x; 1.0337x over previous
//
#include <hip/hip_runtime.h>
#include <cmath>
#include <cstdint>

// ---------------------------------------------------------------------------
// MWT for B=32, N=8192, c=16, k=4, modes=64.
// R15 structure (7 dispatches):
//   front_all (MERGED: dec_fused L0..L3 + transpose_w + twiddle_all in one
//              dispatch — the three are mutually independent; prep rides
//              under dec's 2048 blocks),
//   dec_deep (L4..L12 fused pyramid; 256 blocks x 8 cols, 512 thr),
//   fwd_all (bf16 MFMA, global_load_lds dbuf + XOR-swizzled tiles),
//   middle_all (bf16 MFMA, hi/lo-split A),
//   inv_all (bf16 MFMA; full-K levels: single-stage 64KB swizzled tiles),
//   recon_deep (t0 + i=12..4 fused; 256 blocks x 8 cols, 512 thr),
//   recon_fused (i=3..0 fused in LDS, 512 thr).
// Precision: x-chain fp32; spectral branch bf16 (contributions ~1e-3 scale).
// Lesson bank: staged contiguous global writes beat direct scattered stores
// (R7); stg bank conflicts NOT on critical path (R5); Itw scatter was
// L3-absorbed, not an HBM cost (R10); deep kernels split to 256 blocks (R13).
// ---------------------------------------------------------------------------

typedef __attribute__((ext_vector_type(8))) short bf16x8;
typedef __attribute__((ext_vector_type(4))) float f32x4;

struct Mat84 { float v[8][4]; };
struct Ptrs6 { const float* src[6]; uint16_t* dst[6]; };
struct TwLvls {
  int blkOff[14]; int Nl[13]; int l[13];
  unsigned long long fOff[13]; unsigned long long iOff[13];
};
struct FwdLvls {
  int blkOff[14]; int K[13]; int Kchunk[13];
  unsigned long long fOff[13]; unsigned long long bOff[13]; unsigned long long dOff[13];
};
struct MidLvls {
  int blkOff[14]; int l[13]; int nz[13];
  unsigned long long dOff[13]; unsigned long long sOff[13];
};
struct InvLvls {
  int blkOff[14]; int Nl[13]; int K2l[13];
  unsigned long long iOff[13]; unsigned long long sOff[13]; unsigned long long uOff[13];
};
struct DeepD { unsigned long long dsbOff[13]; };
struct DeepR { unsigned long long uOff[13]; };

__device__ __host__ inline uint16_t f2bf(float f) {
  union { float f; uint32_t u; } cv; cv.f = f;
  uint32_t u = cv.u;
  return (uint16_t)((u + 0x7fffu + ((u >> 16) & 1u)) >> 16);
}
__device__ inline float bf2f(uint16_t h) { return __uint_as_float((uint32_t)h << 16); }
__device__ inline uint32_t pack2(float a, float b) {
  return (uint32_t)f2bf(a) | ((uint32_t)f2bf(b) << 16);
}
__device__ inline bf16x8 negbf(bf16x8 x) {
  bf16x8 r;
#pragma unroll
  for (int j = 0; j < 8; j++) r[j] = (short)(x[j] ^ (short)0x8000);
  return r;
}
// Async global->LDS DMA, 16B per lane: LDS dest = uniform base + lane*16 (HW rule).
__device__ inline void gld_lds16(const uint16_t* g, uint16_t* l) {
  __builtin_amdgcn_global_load_lds(
      (const __attribute__((address_space(1))) void*)g,
      (__attribute__((address_space(3))) void*)l, 16, 0, 0);
}

// ---------------- host: Alpert/Legendre filter construction (k=4) ----------
static double proj_half_h(const double* a, const double* b, bool upper) {
  double prod[7] = {0, 0, 0, 0, 0, 0, 0};
  for (int i = 0; i < 4; i++)
    for (int j = 0; j < 4; j++)
      prod[i + j] += a[i] * b[j];
  for (int n = 0; n < 7; n++)
    if (fabs(prod[n]) < 1e-8) prod[n] = 0.0;
  double s = 0.0;
  for (int n = 0; n < 7; n++) {
    double w = upper ? (1.0 - pow(0.5, n + 1)) / (n + 1) : pow(0.5, n + 1) / (n + 1);
    s += prod[n] * w;
  }
  return s;
}
static double polyval4(const double* c, double x) {
  return c[0] + x * (c[1] + x * (c[2] + x * c[3]));
}

static void compute_filters(Mat84& ecs, Mat84& ecd, Mat84& rce, Mat84& rco) {
  const double leg[4][4] = {{1, 0, 0, 0}, {0, 1, 0, 0}, {-0.5, 0, 1.5, 0}, {0, -1.5, 0, 2.5}};
  double phi_c[4][4] = {}, phi2x_c[4][4] = {};
  const double s2 = sqrt(2.0);
  for (int ki = 0; ki < 4; ki++) {
    double a[4] = {0, 0, 0, 0};
    for (int j = 3; j >= 0; j--) {
      double na[4];
      for (int t = 0; t < 4; t++) { double v = -a[t]; if (t > 0) v += 2.0 * a[t - 1]; na[t] = v; }
      na[0] += leg[ki][j];
      for (int t = 0; t < 4; t++) a[t] = na[t];
    }
    for (int t = 0; t < 4; t++) phi_c[ki][t] = sqrt(2.0 * ki + 1.0) * a[t];
    double bb[4] = {0, 0, 0, 0};
    for (int j = 3; j >= 0; j--) {
      double nb[4];
      for (int t = 0; t < 4; t++) { double v = -bb[t]; if (t > 0) v += 4.0 * bb[t - 1]; nb[t] = v; }
      nb[0] += leg[ki][j];
      for (int t = 0; t < 4; t++) bb[t] = nb[t];
    }
    for (int t = 0; t < 4; t++) phi2x_c[ki][t] = s2 * sqrt(2.0 * ki + 1.0) * bb[t];
  }
  double psi1[4][4] = {}, psi2[4][4] = {};
  for (int ki = 0; ki < 4; ki++) {
    for (int t = 0; t < 4; t++) { psi1[ki][t] = phi2x_c[ki][t]; psi2[ki][t] = 0.0; }
    for (int i = 0; i < 4; i++) {
      double p = proj_half_h(phi2x_c[ki], phi_c[i], false);
      for (int t = 0; t < 4; t++) { psi1[ki][t] -= p * phi_c[i][t]; psi2[ki][t] -= p * phi_c[i][t]; }
    }
    for (int j = 0; j < ki; j++) {
      double p = proj_half_h(phi2x_c[ki], psi1[j], false);
      for (int t = 0; t < 4; t++) { psi1[ki][t] -= p * psi1[j][t]; psi2[ki][t] -= p * psi2[j][t]; }
    }
    double n1 = proj_half_h(psi1[ki], psi1[ki], false);
    double n2 = proj_half_h(psi2[ki], psi2[ki], true);
    double nr = sqrt(n1 + n2);
    for (int t = 0; t < 4; t++) { psi1[ki][t] /= nr; psi2[ki][t] /= nr; }
    for (int t = 0; t < 4; t++) {
      if (fabs(psi1[ki][t]) < 1e-8) psi1[ki][t] = 0.0;
      if (fabs(psi2[ki][t]) < 1e-8) psi2[ki][t] = 0.0;
    }
  }
  const double tq[4] = {-0.8611363115940526, -0.3399810435848563,
                        0.3399810435848563, 0.8611363115940526};
  const double wq[4] = {0.34785484513745385, 0.6521451548625461,
                        0.6521451548625461, 0.34785484513745385};
  double H0[4][4], H1[4][4], G0[4][4], G1[4][4];
  for (int ki = 0; ki < 4; ki++)
    for (int kp = 0; kp < 4; kp++) {
      double h0 = 0, h1 = 0, g0 = 0, g1 = 0;
      for (int m = 0; m < 4; m++) {
        double xm = (tq[m] + 1.0) * 0.5, wm = wq[m] * 0.5;
        double pk = polyval4(phi_c[kp], xm);
        h0 += wm * polyval4(phi_c[ki], xm * 0.5) * pk;
        h1 += wm * polyval4(phi_c[ki], (xm + 1.0) * 0.5) * pk;
        g0 += wm * polyval4(psi1[ki], xm * 0.5) * pk;
        g1 += wm * polyval4(psi2[ki], (xm + 1.0) * 0.5) * pk;
      }
      H0[ki][kp] = h0 / s2; H1[ki][kp] = h1 / s2; G0[ki][kp] = g0 / s2; G1[ki][kp] = g1 / s2;
    }
  for (int i = 0; i < 4; i++)
    for (int j = 0; j < 4; j++) {
      if (fabs(H0[i][j]) < 1e-8) H0[i][j] = 0.0;
      if (fabs(H1[i][j]) < 1e-8) H1[i][j] = 0.0;
      if (fabs(G0[i][j]) < 1e-8) G0[i][j] = 0.0;
      if (fabs(G1[i][j]) < 1e-8) G1[i][j] = 0.0;
    }
  for (int j = 0; j < 4; j++)
    for (int kk = 0; kk < 4; kk++) {
      ecs.v[j][kk]     = (float)H0[kk][j];
      ecs.v[j + 4][kk] = (float)H1[kk][j];
      ecd.v[j][kk]     = (float)G0[kk][j];
      ecd.v[j + 4][kk] = (float)G1[kk][j];
      rce.v[j][kk]     = (float)H0[j][kk];
      rce.v[j + 4][kk] = (float)G0[j][kk];
      rco.v[j][kk]     = (float)H1[j][kk];
      rco.v[j + 4][kk] = (float)G1[j][kk];
    }
}

// ---------------- device kernels -------------------------------------------

// Merged front: blocks [0,2048) = dec_fused L0..L3; [2048,2432) = transpose_w;
// [2432,2432+nbTw) = twiddle_all. All three independent; LDS is a union.
__global__ __launch_bounds__(512) void front_all(
    const float* __restrict__ xin, uint16_t* __restrict__ DSbf,
    float* __restrict__ sOut, DeepD dd, Mat84 ecd, Mat84 ecs,
    Ptrs6 p6, uint16_t* __restrict__ FtwB, uint16_t* __restrict__ ItwB,
    TwLvls tw) {
  __shared__ float smem[10624];   // 42496 B union
  int tid = threadIdx.x;
  int bxg = blockIdx.x;

  if (bxg < 2048) {
    // ================= dec_fused branch =================
    float* bufA = smem;                 // 256*17 floats
    float* bufB = smem + 4352;          // 128*17 floats
    uint16_t* stg = (uint16_t*)(smem + 6528);  // 32*256 u16
    int t = bxg & 15, cc = (bxg >> 4) & 3, b = bxg >> 6;

    // ---- Level 0 ----
    {
      int nbase = t * 256;
      for (int e = tid; e < 1024; e += 512) {
        int n = e >> 2, lci = e & 3;
        const float* r0 = xin + ((size_t)b * 8192 + 2 * (nbase + n)) * 64 + cc * 16 + lci * 4;
        float4 xe = *(const float4*)r0;
        float4 xo = *(const float4*)(r0 + 64);
        float xa[8] = {xe.x, xe.y, xe.z, xe.w, xo.x, xo.y, xo.z, xo.w};
        float d[4] = {0, 0, 0, 0}, s[4] = {0, 0, 0, 0};
#pragma unroll
        for (int j = 0; j < 8; j++) {
          float v = xa[j];
#pragma unroll
          for (int kk = 0; kk < 4; kk++) {
            d[kk] = fmaf(v, ecd.v[j][kk], d[kk]);
            s[kk] = fmaf(v, ecs.v[j][kk], s[kk]);
          }
        }
#pragma unroll
        for (int kk = 0; kk < 4; kk++) {
          bufA[n * 17 + lci * 4 + kk] = s[kk];
          stg[(lci * 4 + kk) * 256 + n] = f2bf(d[kk]);
          stg[(16 + lci * 4 + kk) * 256 + n] = f2bf(s[kk]);
        }
      }
      __syncthreads();
      uint32_t* outu = (uint32_t*)(DSbf + dd.dsbOff[0]);
      const uint32_t* stgu = (const uint32_t*)stg;
      for (int e = tid; e < 32 * 128; e += 512) {
        int r = e >> 7, u = e & 127;
        int grow = (r < 16) ? (cc * 16 + r) : (64 + cc * 16 + (r - 16));
        outu[((((size_t)b * 128 + grow) * 4096 + nbase) >> 1) + u] = stgu[r * 128 + u];
      }
      __syncthreads();
    }
    // ---- Levels 1..3 ----
    float* cur = bufA;
    float* nxt = bufB;
    int M = 128;
    for (int Lev = 1; Lev <= 3; Lev++) {
      int nbase = t * M;
      int Nl = 4096 >> Lev;
      for (int e = tid; e < M * 4; e += 512) {
        int n = e >> 2, lci = e & 3;
        float xa[8];
#pragma unroll
        for (int j = 0; j < 4; j++) {
          xa[j]     = cur[(2 * n) * 17 + lci * 4 + j];
          xa[4 + j] = cur[(2 * n + 1) * 17 + lci * 4 + j];
        }
        float d[4] = {0, 0, 0, 0}, s[4] = {0, 0, 0, 0};
#pragma unroll
        for (int j = 0; j < 8; j++) {
          float v = xa[j];
#pragma unroll
          for (int kk = 0; kk < 4; kk++) {
            d[kk] = fmaf(v, ecd.v[j][kk], d[kk]);
            s[kk] = fmaf(v, ecs.v[j][kk], s[kk]);
          }
        }
#pragma unroll
        for (int kk = 0; kk < 4; kk++) {
          if (Lev < 3) nxt[n * 17 + lci * 4 + kk] = s[kk];
          stg[(lci * 4 + kk) * 256 + n] = f2bf(d[kk]);
          stg[(16 + lci * 4 + kk) * 256 + n] = f2bf(s[kk]);
        }
        if (Lev == 3)
          *(float4*)&sOut[((size_t)b * 512 + nbase + n) * 64 + cc * 16 + lci * 4] =
              make_float4(s[0], s[1], s[2], s[3]);
      }
      __syncthreads();
      int cols = M >> 1, lg = 31 - __builtin_clz(cols);
      uint32_t* outu = (uint32_t*)(DSbf + dd.dsbOff[Lev]);
      const uint32_t* stgu = (const uint32_t*)stg;
      for (int e = tid; e < 32 * cols; e += 512) {
        int r = e >> lg, u = e & (cols - 1);
        int grow = (r < 16) ? (cc * 16 + r) : (64 + cc * 16 + (r - 16));
        outu[((((size_t)b * 128 + grow) * Nl + nbase) >> 1) + u] = stgu[r * 128 + u];
      }
      __syncthreads();
      float* tmp = cur; cur = nxt; nxt = tmp;
      M >>= 1;
    }
  } else if (bxg < 2048 + 384) {
    // ================= transpose_w branch (512 threads) =================
    int bb = bxg - 2048;
    int o = bb & 63, a = bb >> 6;
    float (*tile)[65] = (float(*)[65])smem;
    const float* w = p6.src[a];
    uint16_t* wt = p6.dst[a];
    int mm = tid & 63, irow = tid >> 6;
    for (int i = irow; i < 64; i += 8) tile[i][mm] = w[(((size_t)i * 64 + o) << 6) + mm];
    __syncthreads();
    int ii = tid & 63, mrow = tid >> 6;
    for (int mq = mrow; mq < 64; mq += 8)
      wt[(((size_t)mq * 64 + o) << 6) + ii] = f2bf(tile[ii][mq]);
  } else {
    // ================= twiddle_all branch (512 threads) =================
    int bb = bxg - 2048 - 384;
    uint16_t* ft = (uint16_t*)smem;      // 128*16 u16
    uint16_t* it = ft + 2048;            // 16*136 u16
    int L = 0;
    while (L < 12 && bb >= tw.blkOff[L + 1]) L++;
    int Nl = tw.Nl[L], l = tw.l[L];
    int n0 = (bb - tw.blkOff[L]) * 16;
    uint16_t* Ftw = FtwB + tw.fOff[L];
    uint16_t* Itw = ItwB + tw.iOff[L];
    for (int e = tid; e < 2048; e += 512) {
      int mm = e >> 4, nl = e & 15;
      int n = n0 + nl;
      float fv = 0.f, iv = 0.f;
      if (n < Nl && mm < 2 * l) {
        int m = (mm < l) ? mm : mm - l;
        int t = (m * n) & (Nl - 1);
        float ang = 6.2831853071795864769f * ((float)t / (float)Nl);
        float s, c;
        sincosf(ang, &s, &c);
        float cm = (m == 0 || 2 * m == Nl) ? 1.0f : 2.0f;
        float sc = cm / (float)Nl;
        if (mm < l) { fv = c;  iv = sc * c; }
        else        { fv = -s; iv = -sc * s; }
      }
      ft[mm * 16 + nl] = f2bf(fv);
      it[nl * 136 + mm] = f2bf(iv);
    }
    __syncthreads();
    if (n0 + 16 <= Nl) {
      if (tid < 256) {
        int mm = tid >> 1, half = tid & 1;
        *(uint4*)&Ftw[(size_t)mm * Nl + n0 + half * 8] = *(const uint4*)&ft[mm * 16 + half * 8];
      } else {
        int t2 = tid - 256;
        int nl = t2 >> 4, q = t2 & 15;
        *(uint4*)&Itw[(size_t)(n0 + nl) * 128 + q * 8] = *(const uint4*)&it[nl * 136 + q * 8];
      }
    } else {
      for (int e = tid; e < 2048; e += 512) {
        int mm = e >> 4, nl = e & 15;
        int n = n0 + nl;
        if (n < Nl) {
          Ftw[(size_t)mm * Nl + n] = ft[mm * 16 + nl];
          Itw[(size_t)n * 128 + mm] = it[nl * 136 + mm];
        }
      }
    }
  }
}

// Deep decompose: levels 4..12 fused. Block = (b, c-chunk of 2 c's = 8 cols),
// 256 blocks (1/CU). 512 threads. stg [16][258] (~2-way conflicts, free).
__global__ __launch_bounds__(512) void dec_deep(const float* __restrict__ sIn,
                                                uint16_t* __restrict__ DSbf,
                                                float* __restrict__ sFin,
                                                DeepD dd, Mat84 ecd, Mat84 ecs) {
  __shared__ float bufA[512 * 9];
  __shared__ float bufB[256 * 9];
  __shared__ uint16_t stg[16 * 258];
  int tid = threadIdx.x;
  int b = blockIdx.x >> 3, cc = blockIdx.x & 7;
  for (int e = tid; e < 512 * 2; e += 512) {
    int n = e >> 1, f4 = e & 1;
    float4 v = *(const float4*)&sIn[((size_t)b * 512 + n) * 64 + cc * 8 + f4 * 4];
    bufA[n * 9 + f4 * 4 + 0] = v.x;
    bufA[n * 9 + f4 * 4 + 1] = v.y;
    bufA[n * 9 + f4 * 4 + 2] = v.z;
    bufA[n * 9 + f4 * 4 + 3] = v.w;
  }
  __syncthreads();
  float* cur = bufA;
  float* nxt = bufB;
  int len = 512;
  for (int L = 4; L <= 12; L++) {
    int M = len >> 1;
    for (int e = tid; e < M * 2; e += 512) {
      int n = e >> 1, cl = e & 1;
      float xa[8];
#pragma unroll
      for (int j = 0; j < 4; j++) {
        xa[j]     = cur[(2 * n) * 9 + cl * 4 + j];
        xa[4 + j] = cur[(2 * n + 1) * 9 + cl * 4 + j];
      }
      float d[4] = {0, 0, 0, 0}, s[4] = {0, 0, 0, 0};
#pragma unroll
      for (int j = 0; j < 8; j++) {
        float v = xa[j];
#pragma unroll
        for (int kk = 0; kk < 4; kk++) {
          d[kk] = fmaf(v, ecd.v[j][kk], d[kk]);
          s[kk] = fmaf(v, ecs.v[j][kk], s[kk]);
        }
      }
#pragma unroll
      for (int kk = 0; kk < 4; kk++) {
        nxt[n * 9 + cl * 4 + kk] = s[kk];
        stg[(cl * 4 + kk) * 258 + n] = f2bf(d[kk]);
        stg[(8 + cl * 4 + kk) * 258 + n] = f2bf(s[kk]);
      }
    }
    __syncthreads();
    uint16_t* out = DSbf + dd.dsbOff[L];
    if (M >= 2) {
      int M2 = M >> 1;
      int lg = 31 - __builtin_clz(M2);
      uint32_t* outu = (uint32_t*)out;
      const uint32_t* stgu = (const uint32_t*)stg;
      for (int e = tid; e < 16 * M2; e += 512) {
        int r = e >> lg, u = e & (M2 - 1);
        int grow = (r < 8) ? (cc * 8 + r) : (64 + cc * 8 + (r - 8));
        outu[(((size_t)b * 128 + grow) * M >> 1) + u] = stgu[r * 129 + u];
      }
    } else {
      for (int e = tid; e < 16; e += 512) {
        int grow = (e < 8) ? (cc * 8 + e) : (64 + cc * 8 + (e - 8));
        out[(size_t)b * 128 + grow] = stg[e * 258];
      }
    }
    __syncthreads();
    float* t = cur; cur = nxt; nxt = t;
    len = M;
  }
  for (int e = tid; e < 8; e += 512) sFin[(size_t)b * 64 + cc * 8 + e] = cur[e];
}

// Fwd DFT GEMM, all levels: Dfs slab (z,b) = Ftw(128xK) @ DSbf_b^T chunk.
__global__ __launch_bounds__(256) void fwd_all(const uint16_t* __restrict__ FtwB,
                                               const uint16_t* __restrict__ DSbfB,
                                               float* __restrict__ DfsB, FwdLvls fl) {
  __shared__ uint16_t As[2][4096];
  __shared__ uint16_t Bs[2][4096];
  int bx = blockIdx.x, L = 0;
  while (L < 12 && bx >= fl.blkOff[L + 1]) L++;
  int local = bx - fl.blkOff[L];
  int b = local & 31, z = local >> 5;
  int K = fl.K[L];
  int k0 = z * fl.Kchunk[L];
  int k1 = k0 + fl.Kchunk[L]; if (k1 > K) k1 = K;
  const uint16_t* A = FtwB + fl.fOff[L];
  const uint16_t* Bb = DSbfB + fl.bOff[L] + (size_t)b * 128 * K;
  int tid = threadIdx.x;
  int w = tid >> 6, lane = tid & 63;
  int wr = w >> 1, wc = w & 1;
  int lr = lane & 15, q = lane >> 4;
  f32x4 acc[4][4];
#pragma unroll
  for (int i = 0; i < 4; i++)
#pragma unroll
    for (int j = 0; j < 4; j++) acc[i][j] = (f32x4){0.f, 0.f, 0.f, 0.f};

  if (K >= 32) {
    int rsub = lane >> 2, g = lane & 3;
    int nsteps = (k1 - k0) >> 5;
    auto stage = [&](int buf, int kc) {
#pragma unroll
      for (int j = 0; j < 2; ++j) {
        int c = w * 2 + j;
        int row = c * 16 + rsub;
        int gs = (g ^ ((row >> 1) & 3)) << 3;
        gld_lds16(A + (size_t)row * K + kc + gs, &As[buf][c * 512]);
        gld_lds16(Bb + (size_t)row * K + kc + gs, &Bs[buf][c * 512]);
      }
    };
    stage(0, k0);
    __syncthreads();
    int cur = 0;
    int sw = (lr >> 1) & 3;
    for (int s = 0; s < nsteps; ++s) {
      if (s + 1 < nsteps) stage(cur ^ 1, k0 + ((s + 1) << 5));
      bf16x8 af[4], bfv[4];
#pragma unroll
      for (int t = 0; t < 4; t++) {
        af[t]  = *(const bf16x8*)&As[cur][(wr * 64 + t * 16 + lr) * 32 + ((q ^ sw) << 3)];
        bfv[t] = *(const bf16x8*)&Bs[cur][(wc * 64 + t * 16 + lr) * 32 + ((q ^ sw) << 3)];
      }
#pragma unroll
      for (int mt = 0; mt < 4; mt++)
#pragma unroll
        for (int nt = 0; nt < 4; nt++)
          acc[mt][nt] = __builtin_amdgcn_mfma_f32_16x16x32_bf16(af[mt], bfv[nt], acc[mt][nt], 0, 0, 0);
      __syncthreads();
      cur ^= 1;
    }
  } else {
    for (int s = tid; s < 512; s += 256) {
      int row = s >> 2, k8 = (s & 3) * 8;
      uint16_t ta[8], tb[8];
#pragma unroll
      for (int j = 0; j < 8; j++) {
        ta[j] = (k8 + j < k1) ? A[(size_t)row * K + k8 + j] : (uint16_t)0;
        tb[j] = (k8 + j < k1) ? Bb[(size_t)row * K + k8 + j] : (uint16_t)0;
      }
      *(uint4*)&As[0][row * 32 + k8] = *(const uint4*)ta;
      *(uint4*)&Bs[0][row * 32 + k8] = *(const uint4*)tb;
    }
    __syncthreads();
    bf16x8 af[4], bfv[4];
#pragma unroll
    for (int t = 0; t < 4; t++) {
      af[t]  = *(const bf16x8*)&As[0][(wr * 64 + t * 16 + lr) * 32 + q * 8];
      bfv[t] = *(const bf16x8*)&Bs[0][(wc * 64 + t * 16 + lr) * 32 + q * 8];
    }
#pragma unroll
    for (int mt = 0; mt < 4; mt++)
#pragma unroll
      for (int nt = 0; nt < 4; nt++)
        acc[mt][nt] = __builtin_amdgcn_mfma_f32_16x16x32_bf16(af[mt], bfv[nt], acc[mt][nt], 0, 0, 0);
  }

  float* Cb = DfsB + fl.dOff[L] + ((size_t)z * 32 + b) * 16384;
#pragma unroll
  for (int mt = 0; mt < 4; mt++) {
    int row0 = wr * 64 + mt * 16 + q * 4;
#pragma unroll
    for (int nt = 0; nt < 4; nt++) {
      int col = wc * 64 + nt * 16 + lr;
#pragma unroll
      for (int r = 0; r < 4; r++)
        Cb[(size_t)(row0 + r) * 128 + col] = acc[mt][nt][r];
    }
  }
}

// Spectral mix, all levels — MFMA version.
__global__ __launch_bounds__(256) void middle_all(
    const float* __restrict__ DfsB,
    const uint16_t* __restrict__ wAr, const uint16_t* __restrict__ wAi,
    const uint16_t* __restrict__ wBr, const uint16_t* __restrict__ wBi,
    const uint16_t* __restrict__ wCr, const uint16_t* __restrict__ wCi,
    uint16_t* __restrict__ SpecTB, MidLvls ml) {
  __shared__ uint16_t Bs[6 * 64 * 64];
  __shared__ uint16_t As[8 * 32 * 64];
  int bx = blockIdx.x, L = 0;
  while (L < 12 && bx >= ml.blkOff[L + 1]) L++;
  int m = bx - ml.blkOff[L];
  int l = ml.l[L], nz = ml.nz[L];
  const float* Dfs = DfsB + ml.dOff[L];
  uint16_t* SpecT = SpecTB + ml.sOff[L];
  int tid = threadIdx.x;

#pragma unroll
  for (int a = 0; a < 6; a++) {
    const uint16_t* wpa = (a == 0) ? wAr : (a == 1) ? wAi : (a == 2) ? wBr
                        : (a == 3) ? wBi : (a == 4) ? wCr : wCi;
#pragma unroll
    for (int t0 = 0; t0 < 512; t0 += 256) {
      int t = t0 + tid;
      int o = t >> 3, g = t & 7;
      uint4 v = *(const uint4*)&wpa[(((size_t)m * 64 + o) << 6) + (g << 3)];
      *(uint4*)((char*)Bs + a * 8192 + o * 128 + (((g ^ (o & 7)) << 4))) = v;
    }
  }
  for (int e = tid; e < 2048; e += 256) {
    int c4 = (e & 31) * 4, r = (e >> 5) & 1, bb = e >> 6;
    size_t row = r ? (size_t)(l + m) : (size_t)m;
    float4 s = make_float4(0.f, 0.f, 0.f, 0.f);
    for (int z = 0; z < nz; z++) {
      float4 v = *(const float4*)&Dfs[((((size_t)z * 32 + bb) * 128 + row) << 7) + c4];
      s.x += v.x; s.y += v.y; s.z += v.z; s.w += v.w;
    }
    int vec = r + ((c4 >= 64) ? 2 : 0);
    int i0 = c4 & 63;
    float f[4] = {s.x, s.y, s.z, s.w};
    uint16_t hi[4], lo[4];
#pragma unroll
    for (int j = 0; j < 4; j++) {
      hi[j] = f2bf(f[j]);
      lo[j] = f2bf(f[j] - bf2f(hi[j]));
    }
    int g = i0 >> 3, w8 = (i0 & 7) * 2;
    char* ph = (char*)As + ((vec * 2 + 0) * 32 + bb) * 128 + ((g ^ (bb & 7)) << 4) + w8;
    char* pl = (char*)As + ((vec * 2 + 1) * 32 + bb) * 128 + ((g ^ (bb & 7)) << 4) + w8;
    *(uint2*)ph = make_uint2((uint32_t)hi[0] | ((uint32_t)hi[1] << 16),
                             (uint32_t)hi[2] | ((uint32_t)hi[3] << 16));
    *(uint2*)pl = make_uint2((uint32_t)lo[0] | ((uint32_t)lo[1] << 16),
                             (uint32_t)lo[2] | ((uint32_t)lo[3] << 16));
  }
  __syncthreads();

  int w = tid >> 6, lane = tid & 63;
  int lr = lane & 15, q = lane >> 4;
  f32x4 acc[2][4];
#pragma unroll
  for (int i = 0; i < 2; i++)
#pragma unroll
    for (int j = 0; j < 4; j++) acc[i][j] = (f32x4){0.f, 0.f, 0.f, 0.f};

  auto combo = [&](int v, int a, int ng) {
    bf16x8 bf[4][2];
#pragma unroll
    for (int nt = 0; nt < 4; nt++) {
      int o = nt * 16 + lr;
#pragma unroll
      for (int ks = 0; ks < 2; ks++) {
        int g = ks * 4 + q;
        bf[nt][ks] = *(const bf16x8*)((const char*)Bs + a * 8192 + o * 128 +
                                      ((g ^ (o & 7)) << 4));
      }
    }
#pragma unroll
    for (int p = 0; p < 2; p++) {
#pragma unroll
      for (int mt = 0; mt < 2; mt++) {
        int bb = mt * 16 + lr;
        const char* ab = (const char*)As + ((v * 2 + p) * 32 + bb) * 128;
        bf16x8 a0 = *(const bf16x8*)(ab + (((0 + q) ^ (bb & 7)) << 4));
        bf16x8 a1 = *(const bf16x8*)(ab + (((4 + q) ^ (bb & 7)) << 4));
        if (ng) { a0 = negbf(a0); a1 = negbf(a1); }
#pragma unroll
        for (int nt = 0; nt < 4; nt++) {
          acc[mt][nt] = __builtin_amdgcn_mfma_f32_16x16x32_bf16(a0, bf[nt][0], acc[mt][nt], 0, 0, 0);
          acc[mt][nt] = __builtin_amdgcn_mfma_f32_16x16x32_bf16(a1, bf[nt][1], acc[mt][nt], 0, 0, 0);
        }
      }
    }
  };
  if (w == 0) {
    combo(0, 0, 0); combo(1, 1, 1); combo(2, 2, 0); combo(3, 3, 1);
  } else if (w == 1) {
    combo(1, 0, 0); combo(0, 1, 0); combo(3, 2, 0); combo(2, 3, 0);
  } else if (w == 2) {
    combo(0, 4, 0); combo(1, 5, 1);
  } else {
    combo(1, 4, 0); combo(0, 5, 0);
  }

  int krow = (w & 1) ? (l + m) : m;
  int colbase = (w >= 2) ? 64 : 0;
#pragma unroll
  for (int mt = 0; mt < 2; mt++) {
#pragma unroll
    for (int nt = 0; nt < 4; nt++) {
#pragma unroll
      for (int r = 0; r < 4; r++) {
        int bb = mt * 16 + q * 4 + r;
        int oo = nt * 16 + lr;
        SpecT[((size_t)bb * 128 + colbase + oo) * 128 + krow] = f2bf(acc[mt][nt][r]);
      }
    }
  }
}

// Inv DFT GEMM, all levels: Y_b (Nl x 128) = Itw(Nl x 128) @ Spec_b (128x128).
__global__ __launch_bounds__(256) void inv_all(const uint16_t* __restrict__ ItwB,
                                               const uint16_t* __restrict__ SpecTB,
                                               uint16_t* __restrict__ UdB,
                                               uint16_t* __restrict__ UsB, InvLvls il) {
  __shared__ uint16_t lds[32768];
  int bx = blockIdx.x, L = 0;
  while (L < 12 && bx >= il.blkOff[L + 1]) L++;
  int local = bx - il.blkOff[L];
  int b = local & 31, n0 = (local >> 5) * 128;
  int Nl = il.Nl[L], K2l = il.K2l[L];
  const uint16_t* A = ItwB + il.iOff[L];
  const uint16_t* Bb = SpecTB + il.sOff[L] + (size_t)b * 128 * 128;
  uint16_t* Ud = UdB + il.uOff[L];
  uint16_t* Us = UsB + il.uOff[L];
  int tid = threadIdx.x;
  int w = tid >> 6, lane = tid & 63;
  int wr = w >> 1, wc = w & 1;
  int lr = lane & 15, q = lane >> 4;
  f32x4 acc[4][4];
#pragma unroll
  for (int i = 0; i < 4; i++)
#pragma unroll
    for (int j = 0; j < 4; j++) acc[i][j] = (f32x4){0.f, 0.f, 0.f, 0.f};

  if (K2l == 128) {
    uint16_t* As0 = lds;
    uint16_t* Bs0 = lds + 16384;
    int rsub = lane >> 4, p = lane & 15;
#pragma unroll
    for (int i = 0; i < 8; i++) {
      int rowb = w * 32 + i * 4;
      int row = rowb + rsub;
      int gs = (p ^ (row & 7)) << 3;
      gld_lds16(A + (size_t)(n0 + row) * 128 + gs, As0 + rowb * 128);
      gld_lds16(Bb + (size_t)row * 128 + gs, Bs0 + rowb * 128);
    }
    __syncthreads();
    int sw = lr & 7;
#pragma unroll
    for (int kc = 0; kc < 4; kc++) {
      bf16x8 af[4], bfv[4];
#pragma unroll
      for (int t = 0; t < 4; t++) {
        int g = kc * 4 + q;
        af[t]  = *(const bf16x8*)&As0[(wr * 64 + t * 16 + lr) * 128 + ((g ^ sw) << 3)];
        bfv[t] = *(const bf16x8*)&Bs0[(wc * 64 + t * 16 + lr) * 128 + ((g ^ sw) << 3)];
      }
#pragma unroll
      for (int mt = 0; mt < 4; mt++)
#pragma unroll
        for (int nt = 0; nt < 4; nt++)
          acc[mt][nt] = __builtin_amdgcn_mfma_f32_16x16x32_bf16(af[mt], bfv[nt], acc[mt][nt], 0, 0, 0);
    }
    __syncthreads();
#pragma unroll
    for (int mt = 0; mt < 4; mt++)
#pragma unroll
      for (int nt = 0; nt < 4; nt++)
#pragma unroll
        for (int r = 0; r < 4; r++)
          lds[(wr * 64 + mt * 16 + q * 4 + r) * 132 + wc * 64 + nt * 16 + lr] =
              f2bf(acc[mt][nt][r]);
    __syncthreads();
    uint16_t* Udb = Ud + ((size_t)b * Nl + n0) * 64;
    uint16_t* Usb = Us + ((size_t)b * Nl + n0) * 64;
#pragma unroll
    for (int i = 0; i < 4; i++) {
      int f = i * 256 + tid;
      int row = f >> 3, c8 = (f & 7) * 8;
      *(uint4*)(Udb + (size_t)f * 8) = *(const uint4*)&lds[row * 132 + c8];
      *(uint4*)(Usb + (size_t)f * 8) = *(const uint4*)&lds[row * 132 + 64 + c8];
    }
    return;
  }

  uint16_t* As0 = lds;
  uint16_t* Bs0 = lds + 4096;
  for (int kc = 0; kc < 128; kc += 32) {
    for (int s = tid; s < 512; s += 256) {
      int row = s >> 2, k8 = (s & 3) * 8;
      int kg = kc + k8;
      *(uint4*)&As0[row * 32 + k8] = *(const uint4*)&A[((size_t)(n0 + row)) * 128 + kg];
      uint16_t tb[8];
      if (kg + 8 <= K2l) {
        *(uint4*)tb = *(const uint4*)&Bb[(size_t)row * 128 + kg];
      } else {
#pragma unroll
        for (int j = 0; j < 8; j++)
          tb[j] = (kg + j < K2l) ? Bb[(size_t)row * 128 + kg + j] : (uint16_t)0;
      }
      *(uint4*)&Bs0[row * 32 + k8] = *(const uint4*)tb;
    }
    __syncthreads();
    bf16x8 af[4], bfv[4];
#pragma unroll
    for (int t = 0; t < 4; t++) {
      af[t]  = *(const bf16x8*)&As0[(wr * 64 + t * 16 + lr) * 32 + q * 8];
      bfv[t] = *(const bf16x8*)&Bs0[(wc * 64 + t * 16 + lr) * 32 + q * 8];
    }
#pragma unroll
    for (int mt = 0; mt < 4; mt++)
#pragma unroll
      for (int nt = 0; nt < 4; nt++)
        acc[mt][nt] = __builtin_amdgcn_mfma_f32_16x16x32_bf16(af[mt], bfv[nt], acc[mt][nt], 0, 0, 0);
    __syncthreads();
  }
#pragma unroll
  for (int mt = 0; mt < 4; mt++) {
    int row0 = wr * 64 + mt * 16 + q * 4;
#pragma unroll
    for (int nt = 0; nt < 4; nt++) {
      int col = wc * 64 + nt * 16 + lr;
#pragma unroll
      for (int r = 0; r < 4; r++) {
        int n = n0 + row0 + r;
        if (n < Nl) {
          uint16_t v = f2bf(acc[mt][nt][r]);
          if (col < 64) Ud[((size_t)b * Nl + n) * 64 + col] = v;
          else          Us[((size_t)b * Nl + n) * 64 + (col - 64)] = v;
        }
      }
    }
  }
}

// Deep recon: t0 on s^13, then levels i=12..4 fused. Block = (b, 8-col chunk),
// 256 blocks, 512 threads; writes x^4 (b, 512, 64) fp32.
__global__ __launch_bounds__(512) void recon_deep(const float* __restrict__ sFin,
                                                  const float* __restrict__ t0w,
                                                  const float* __restrict__ t0b,
                                                  const uint16_t* __restrict__ UdB,
                                                  const uint16_t* __restrict__ UsB,
                                                  float* __restrict__ xOut,
                                                  DeepR rl, Mat84 rce, Mat84 rco) {
  __shared__ float bufA[512 * 9];
  __shared__ float bufB[256 * 9];
  int tid = threadIdx.x;
  int b = blockIdx.x >> 3, cc = blockIdx.x & 7;
  if (tid < 8) {
    int cl = tid >> 2, kk = tid & 3;
    const float* sp = sFin + (size_t)b * 64 + cc * 8 + cl * 4;
    float v = t0b[kk];
#pragma unroll
    for (int k2 = 0; k2 < 4; k2++) v += t0w[kk * 4 + k2] * sp[k2];
    bufB[cl * 4 + kk] = v;
  }
  __syncthreads();
  float* cur = bufB;
  float* nxt = bufA;
  int M = 1;
  for (int i = 12; i >= 4; i--) {
    const uint16_t* Ud = UdB + rl.uOff[i];
    const uint16_t* Us = UsB + rl.uOff[i];
    for (int e = tid; e < M * 2; e += 512) {
      int n = e >> 1, cl = e & 1;
      size_t ua = ((size_t)b * M + n) * 64 + cc * 8 + cl * 4;
      ushort4 uu = *(const ushort4*)&Us[ua];
      ushort4 dd = *(const ushort4*)&Ud[ua];
      float t[8];
      t[0] = cur[n * 9 + cl * 4 + 0] + bf2f(uu.x);
      t[1] = cur[n * 9 + cl * 4 + 1] + bf2f(uu.y);
      t[2] = cur[n * 9 + cl * 4 + 2] + bf2f(uu.z);
      t[3] = cur[n * 9 + cl * 4 + 3] + bf2f(uu.w);
      t[4] = bf2f(dd.x); t[5] = bf2f(dd.y); t[6] = bf2f(dd.z); t[7] = bf2f(dd.w);
      float ev[4] = {0, 0, 0, 0}, ov[4] = {0, 0, 0, 0};
#pragma unroll
      for (int j = 0; j < 8; j++) {
        float v = t[j];
#pragma unroll
        for (int kk = 0; kk < 4; kk++) {
          ev[kk] = fmaf(v, rce.v[j][kk], ev[kk]);
          ov[kk] = fmaf(v, rco.v[j][kk], ov[kk]);
        }
      }
#pragma unroll
      for (int kk = 0; kk < 4; kk++) {
        nxt[(2 * n) * 9 + cl * 4 + kk] = ev[kk];
        nxt[(2 * n + 1) * 9 + cl * 4 + kk] = ov[kk];
      }
    }
    __syncthreads();
    float* t = cur; cur = nxt; nxt = t;
    M <<= 1;
  }
  for (int e = tid; e < 512 * 2; e += 512) {
    int n = e >> 1, f4 = e & 1;
    float4 v = make_float4(cur[n * 9 + f4 * 4 + 0], cur[n * 9 + f4 * 4 + 1],
                           cur[n * 9 + f4 * 4 + 2], cur[n * 9 + f4 * 4 + 3]);
    *(float4*)&xOut[((size_t)b * 512 + n) * 64 + cc * 8 + f4 * 4] = v;
  }
}

// Fused recon i=3..0: block = (b, c-chunk of 16 ch, tile of 512 final rows).
// 512 threads.
__global__ __launch_bounds__(512) void recon_fused(const float* __restrict__ xin,
                                                   const uint16_t* __restrict__ UdB,
                                                   const uint16_t* __restrict__ UsB,
                                                   float* __restrict__ out,
                                                   DeepR rl, Mat84 rce, Mat84 rco) {
  __shared__ float bufA[256 * 17];
  __shared__ float bufB[256 * 17];
  int tid = threadIdx.x;
  int bx = blockIdx.x;
  int t = bx & 15, cc = (bx >> 4) & 3, b = bx >> 6;

  // ---- i = 3: SD (32 rows) -> bufA (64 rows) ----
  {
    int nbase = t * 32;
    const uint16_t* Ud = UdB + rl.uOff[3];
    const uint16_t* Us = UsB + rl.uOff[3];
    for (int e = tid; e < 128; e += 512) {
      int n = e >> 2, lci = e & 3;
      size_t ua = ((size_t)b * 512 + nbase + n) * 64 + cc * 16 + lci * 4;
      float4 xv = *(const float4*)&xin[ua];
      ushort4 uu = *(const ushort4*)&Us[ua];
      ushort4 dd = *(const ushort4*)&Ud[ua];
      float tv[8] = {xv.x + bf2f(uu.x), xv.y + bf2f(uu.y), xv.z + bf2f(uu.z),
                     xv.w + bf2f(uu.w), bf2f(dd.x), bf2f(dd.y), bf2f(dd.z), bf2f(dd.w)};
      float ev[4] = {0, 0, 0, 0}, ov[4] = {0, 0, 0, 0};
#pragma unroll
      for (int j = 0; j < 8; j++) {
        float v = tv[j];
#pragma unroll
        for (int kk = 0; kk < 4; kk++) {
          ev[kk] = fmaf(v, rce.v[j][kk], ev[kk]);
          ov[kk] = fmaf(v, rco.v[j][kk], ov[kk]);
        }
      }
#pragma unroll
      for (int kk = 0; kk < 4; kk++) {
        bufA[(2 * n) * 17 + lci * 4 + kk] = ev[kk];
        bufA[(2 * n + 1) * 17 + lci * 4 + kk] = ov[kk];
      }
    }
    __syncthreads();
  }
  // ---- i = 2, 1, 0 ----
  float* cur = bufA;
  float* nxt = bufB;
  int m = 64;
  for (int i = 2; i >= 0; i--) {
    int Mlev = 8192 >> (i + 1);
    int nbase = t * m;
    const uint16_t* Ud = UdB + rl.uOff[i];
    const uint16_t* Us = UsB + rl.uOff[i];
    for (int e = tid; e < m * 4; e += 512) {
      int n = e >> 2, lci = e & 3;
      size_t ua = ((size_t)b * Mlev + nbase + n) * 64 + cc * 16 + lci * 4;
      ushort4 uu = *(const ushort4*)&Us[ua];
      ushort4 dd = *(const ushort4*)&Ud[ua];
      float tv[8];
      tv[0] = cur[n * 17 + lci * 4 + 0] + bf2f(uu.x);
      tv[1] = cur[n * 17 + lci * 4 + 1] + bf2f(uu.y);
      tv[2] = cur[n * 17 + lci * 4 + 2] + bf2f(uu.z);
      tv[3] = cur[n * 17 + lci * 4 + 3] + bf2f(uu.w);
      tv[4] = bf2f(dd.x); tv[5] = bf2f(dd.y); tv[6] = bf2f(dd.z); tv[7] = bf2f(dd.w);
      float ev[4] = {0, 0, 0, 0}, ov[4] = {0, 0, 0, 0};
#pragma unroll
      for (int j = 0; j < 8; j++) {
        float v = tv[j];
#pragma unroll
        for (int kk = 0; kk < 4; kk++) {
          ev[kk] = fmaf(v, rce.v[j][kk], ev[kk]);
          ov[kk] = fmaf(v, rco.v[j][kk], ov[kk]);
        }
      }
      if (i > 0) {
#pragma unroll
        for (int kk = 0; kk < 4; kk++) {
          nxt[(2 * n) * 17 + lci * 4 + kk] = ev[kk];
          nxt[(2 * n + 1) * 17 + lci * 4 + kk] = ov[kk];
        }
      } else {
        size_t ob = ((size_t)b * 8192 + 2 * (nbase + n)) * 64 + cc * 16 + lci * 4;
        *(float4*)&out[ob] = make_float4(ev[0], ev[1], ev[2], ev[3]);
        *(float4*)&out[ob + 64] = make_float4(ov[0], ov[1], ov[2], ov[3]);
      }
    }
    __syncthreads();
    float* tmp = cur; cur = nxt; nxt = tmp;
    m <<= 1;
  }
}

// ---------------- host orchestration ---------------------------------------
extern "C" void kernel_launch(void* const* d_in, const int* in_sizes, int n_in,
                              void* d_out, int out_size, void* d_ws, size_t ws_size,
                              hipStream_t stream) {
  const float* x_in = (const float*)d_in[0];
  const float* t0w = (const float*)d_in[7];
  const float* t0b = (const float*)d_in[8];

  Mat84 ECS, ECD, RCE, RCO;
  compute_filters(ECS, ECD, RCE, RCO);

  int NlA[13], lA[13], nzA[13], KchA[13];
  size_t fOff[13], iOff[13], uOffA[13], dsbOff[13], dOff[13], sOff[13];
  size_t fo = 0, io = 0, uo = 0, db = 0, df = 0;
  for (int L = 0; L < 13; L++) {
    int Nl = 8192 >> (L + 1);
    int l = Nl / 2 + 1; if (l > 64) l = 64;
    NlA[L] = Nl; lA[L] = l;
    nzA[L] = (L == 0) ? 4 : (L == 1) ? 2 : 1;
    KchA[L] = Nl / nzA[L];
    fOff[L] = fo; fo += (size_t)128 * Nl;
    iOff[L] = io; io += (size_t)Nl * 128;
    uOffA[L] = uo; uo += (size_t)32 * 64 * Nl;
    dsbOff[L] = db; db += (size_t)32 * 128 * Nl;
    dOff[L] = df; df += (size_t)nzA[L] * 32 * 128 * 128;
    sOff[L] = (size_t)L * 32 * 128 * 128;
  }
  io += 128 * 128;  // inv_all A-row overrun slack at partial tiles

  char* base = (char*)d_ws;
  size_t off = 0;
  auto alloc = [&](size_t bytes) -> char* {
    char* p = base + off;
    off += (bytes + 255) & ~(size_t)255;
    return p;
  };
  float*    SD    = (float*)alloc((size_t)32 * 512 * 64 * 4);
  float*    SFin  = (float*)alloc((size_t)32 * 64 * 4);
  uint16_t* Ud    = (uint16_t*)alloc(uo * 2);
  uint16_t* Us    = (uint16_t*)alloc(uo * 2);
  float*    Dfs   = (float*)alloc(df * 4);
  uint16_t* SpecT = (uint16_t*)alloc((size_t)13 * 32 * 128 * 128 * 2);
  uint16_t* DSbf  = (uint16_t*)alloc(db * 2);
  uint16_t* Ftw   = (uint16_t*)alloc(fo * 2);
  uint16_t* Itw   = (uint16_t*)alloc(io * 2);
  uint16_t* wT[6];
  for (int a = 0; a < 6; a++) wT[a] = (uint16_t*)alloc((size_t)64 * 64 * 64 * 2);

  Ptrs6 p6;
  for (int a = 0; a < 6; a++) { p6.src[a] = (const float*)d_in[1 + a]; p6.dst[a] = wT[a]; }

  TwLvls tw;
  int bo = 0;
  for (int L = 0; L < 13; L++) {
    tw.blkOff[L] = bo;
    bo += (NlA[L] + 15) / 16;
    tw.Nl[L] = NlA[L]; tw.l[L] = lA[L];
    tw.fOff[L] = fOff[L]; tw.iOff[L] = iOff[L];
  }
  tw.blkOff[13] = bo;
  int nbTw = bo;

  DeepD dd;
  for (int L = 0; L < 13; L++) dd.dsbOff[L] = dsbOff[L];

  // 1: merged front (dec_fused + transpose_w + twiddle_all)
  front_all<<<2048 + 384 + nbTw, 512, 0, stream>>>(x_in, DSbf, SD, dd, ECD, ECS,
                                                   p6, Ftw, Itw, tw);

  // 2: deep decompose L4..L12 (256 blocks x 512 threads)
  dec_deep<<<256, 512, 0, stream>>>(SD, DSbf, SFin, dd, ECD, ECS);

  // 3: fwd GEMM all levels
  FwdLvls fl;
  bo = 0;
  for (int L = 0; L < 13; L++) {
    fl.blkOff[L] = bo; bo += 32 * nzA[L];
    fl.K[L] = NlA[L]; fl.Kchunk[L] = KchA[L];
    fl.fOff[L] = fOff[L]; fl.bOff[L] = dsbOff[L]; fl.dOff[L] = dOff[L];
  }
  fl.blkOff[13] = bo;
  fwd_all<<<bo, 256, 0, stream>>>(Ftw, DSbf, Dfs, fl);

  // 4: spectral mix all levels
  MidLvls ml;
  bo = 0;
  for (int L = 0; L < 13; L++) {
    ml.blkOff[L] = bo; bo += lA[L];
    ml.l[L] = lA[L]; ml.nz[L] = nzA[L];
    ml.dOff[L] = dOff[L]; ml.sOff[L] = sOff[L];
  }
  ml.blkOff[13] = bo;
  middle_all<<<bo, 256, 0, stream>>>(Dfs, wT[0], wT[1], wT[2], wT[3], wT[4], wT[5], SpecT, ml);

  // 5: inv GEMM all levels
  InvLvls il;
  bo = 0;
  for (int L = 0; L < 13; L++) {
    il.blkOff[L] = bo; bo += ((NlA[L] + 127) / 128) * 32;
    il.Nl[L] = NlA[L]; il.K2l[L] = 2 * lA[L];
    il.iOff[L] = iOff[L]; il.sOff[L] = sOff[L]; il.uOff[L] = uOffA[L];
  }
  il.blkOff[13] = bo;
  inv_all<<<bo, 256, 0, stream>>>(Itw, SpecT, Ud, Us, il);

  DeepR rl;
  for (int L = 0; L < 13; L++) rl.uOff[L] = uOffA[L];

  // 6: deep recon (t0 + i=12..4) -> x^4 in SD (256 blocks x 512 threads)
  recon_deep<<<256, 512, 0, stream>>>(SFin, t0w, t0b, Ud, Us, SD, rl, RCE, RCO);

  // 7: fused recon i=3..0 -> output (512 threads)
  recon_fused<<<2048, 512, 0, stream>>>(SD, Ud, Us, (float*)d_out, rl, RCE, RCO);
}